// Round 3
// baseline (973.386 us; speedup 1.0000x reference)
//
#include <hip/hip_runtime.h>
#include <hip/hip_bf16.h>
#include <math.h>

#define BB 2
#define SS 2048
#define DD 2048
#define HH 16
#define DHH 128
#define MM (BB*SS)   // 4096

typedef __attribute__((ext_vector_type(8))) short bf16x8;
typedef __attribute__((ext_vector_type(4))) float f32x4;

#define AS1 __attribute__((address_space(1)))
#define AS3 __attribute__((address_space(3)))
#define GLOAD_LDS16(g, l) __builtin_amdgcn_global_load_lds((const AS1 void*)(g), (AS3 void*)(l), 16, 0, 0)

#if __has_builtin(__builtin_amdgcn_exp2f)
#define EXP2F(x) __builtin_amdgcn_exp2f(x)
#else
#define EXP2F(x) exp2f(x)
#endif

__device__ __forceinline__ float b2f(short s) {
  union { unsigned int u; float f; } v;
  v.u = ((unsigned int)(unsigned short)s) << 16;
  return v.f;
}
__device__ __forceinline__ short f2b(float f) {
  union { float f; unsigned int u; } v; v.f = f;
  unsigned int u = v.u;
  u += 0x7fffu + ((u >> 16) & 1u);   // round-to-nearest-even
  return (short)(u >> 16);
}
// fast round-half-up; valid for non-negative finite values
__device__ __forceinline__ short f2b_fast(float f) {
  union { float f; unsigned int u; } v; v.f = f;
  return (short)((v.u + 0x8000u) >> 16);
}

// ---- DPP helpers (VALU pipe, no LDS ops) ----
template<int CTRL>
__device__ __forceinline__ float dppf(float x) {
  int xi = __builtin_bit_cast(int, x);
  int r = __builtin_amdgcn_update_dpp(0, xi, CTRL, 0xf, 0xf, true);
  return __builtin_bit_cast(float, r);
}
__device__ __forceinline__ float rmax16(float x) {
  x = fmaxf(x, dppf<0xB1>(x));   // quad_perm xor1
  x = fmaxf(x, dppf<0x4E>(x));   // quad_perm xor2
  x = fmaxf(x, dppf<0x141>(x));  // row_half_mirror
  x = fmaxf(x, dppf<0x140>(x));  // row_mirror
  return x;
}
__device__ __forceinline__ float rsum16(float x) {
  x += dppf<0xB1>(x);
  x += dppf<0x4E>(x);
  x += dppf<0x141>(x);
  x += dppf<0x140>(x);
  return x;
}

// ---------------- fp32 -> bf16 convert, all 5 tensors in one launch ----------------
__global__ void cvt_all(const float* __restrict__ x,  const float* __restrict__ wq,
                        const float* __restrict__ wk, const float* __restrict__ wv,
                        const float* __restrict__ wo,
                        short* __restrict__ xb,  short* __restrict__ wqb,
                        short* __restrict__ wkb, short* __restrict__ wvb,
                        short* __restrict__ wob) {
  int i = blockIdx.x * blockDim.x + threadIdx.x;   // float4 index
  const float* src; short* dst; int off;
  if (i < 2097152) { src = x; dst = xb; off = i; }
  else {
    int j = i - 2097152;
    int w = j >> 20; off = j & 1048575;
    src = (w == 0) ? wq : (w == 1) ? wk : (w == 2) ? wv : wo;
    dst = (w == 0) ? wqb : (w == 1) ? wkb : (w == 2) ? wvb : wob;
  }
  float4 v = ((const float4*)src)[i < 2097152 ? off : off];
  short4 o;
  o.x = f2b(v.x); o.y = f2b(v.y); o.z = f2b(v.z); o.w = f2b(v.w);
  ((short4*)dst)[off] = o;
}

// ---------------- Fused QKV GEMM: 256x256 tile, 8-phase schedule -----------------
// 8 waves (2M x 4N), BK=64, 128 KiB double-buffered LDS, T2 swizzle via
// pre-swizzled global source (global_load_lds writes linearly), counted vmcnt.
// RoPE fused in epilogue; Q scaled by log2(e)/sqrt(DH) (exp2-domain softmax).
//
// LDS fragment read swizzle: linear slot s holds global col-slot (s ^ (row&7)).
#define LDA(cb, mt, kk) (*(const bf16x8*)((const char*)smA + (cb)*32768 + \
    (wm*128 + (mt)*16 + l16)*128 + (((kk)*64 + quad*16) ^ ((l16 & 7) << 4))))
#define LDB(cb, nt, kk) (*(const bf16x8*)((const char*)smB + (cb)*32768 + \
    (wn*64 + (nt)*16 + l16)*128 + (((kk)*64 + quad*16) ^ ((l16 & 7) << 4))))
// stage one 128-row half (2 x global_load_lds, 16B/lane, linear LDS dest)
#define STGA(b, t, h) do { \
    GLOAD_LDS16(aBase + (size_t)((h)*128) * DD + (t)*64,      smA + (b)*16384 + ((h)*128)*64 + wst); \
    GLOAD_LDS16(aBase + (size_t)((h)*128 + 64) * DD + (t)*64, smA + (b)*16384 + ((h)*128 + 64)*64 + wst); } while(0)
#define STGB(b, t, h) do { \
    GLOAD_LDS16(bBase + (size_t)((h)*128) * DD + (t)*64,      smB + (b)*16384 + ((h)*128)*64 + wst); \
    GLOAD_LDS16(bBase + (size_t)((h)*128 + 64) * DD + (t)*64, smB + (b)*16384 + ((h)*128 + 64)*64 + wst); } while(0)
#define MFMA_Q(MT0, NT0) do { \
    __builtin_amdgcn_s_setprio(1); \
    _Pragma("unroll") \
    for (int mt = 0; mt < 4; ++mt) \
      _Pragma("unroll") \
      for (int nt = 0; nt < 2; ++nt) \
        _Pragma("unroll") \
        for (int kk = 0; kk < 2; ++kk) \
          acc[(MT0) + mt][(NT0) + nt] = __builtin_amdgcn_mfma_f32_16x16x32_bf16( \
              af[mt][kk], bf[(NT0) + nt][kk], acc[(MT0) + mt][(NT0) + nt], 0, 0, 0); \
    __builtin_amdgcn_s_setprio(0); } while(0)

__global__ __launch_bounds__(512, 2)
void gemm_qkv(const short* __restrict__ A,
              const short* __restrict__ Wq, const short* __restrict__ Wk,
              const short* __restrict__ Wv, const int* __restrict__ pos,
              short* __restrict__ Qo, short* __restrict__ Ko, short* __restrict__ Vo) {
  __shared__ __align__(16) short sm[65536];   // 128 KiB: A[2][256][64] | B[2][256][64]
  const int tid = threadIdx.x;
  const int lane = tid & 63;
  const int wave = tid >> 6;                  // 0..7
  const int quad = lane >> 4, l16 = lane & 15;
  const int wm = wave >> 2, wn = wave & 3;    // wave tile: 128 rows x 64 cols
  const int wsel = blockIdx.x >> 3;           // 0=Q 1=K 2=V
  const short* Bw = (wsel == 0) ? Wq : (wsel == 1) ? Wk : Wv;
  short* Cout = (wsel == 0) ? Qo : (wsel == 1) ? Ko : Vo;
  const int bn = (blockIdx.x & 7) * 256;
  const int bm = blockIdx.y * 256;

  short* smA = sm;                 // bufs at +0, +16384 (shorts)
  short* smB = sm + 32768;         // bufs at +0, +16384 (shorts)
  const int wst = wave * 512;      // wave's staging base (8 rows x 64 shorts)

  // staging source: row (tid>>3) of the 64-row group; col pre-swizzled so that
  // linear LDS write + XOR read reconstructs the tile (both-sides rule).
  const int srow = tid >> 3;                          // 0..63
  const int scol = ((tid & 7) ^ (srow & 7)) * 8;      // shorts
  const short* aBase = A  + (size_t)(bm + srow) * DD + scol;
  const short* bBase = Bw + (size_t)(bn + srow) * DD + scol;

  f32x4 acc[8][4] = {};
  bf16x8 af[4][2], bf[4][2];

  // ---- prologue: tile0 (A+B) + tile1 (B); leave tile1's B in flight ----
  STGA(0, 0, 0); STGA(0, 0, 1);
  STGB(0, 0, 0); STGB(0, 0, 1);
  STGB(1, 1, 0); STGB(1, 1, 1);
  asm volatile("s_waitcnt vmcnt(4)" ::: "memory");   // tile0 fully resident
  __builtin_amdgcn_s_barrier();

  for (int t = 0; t < 32; ++t) {
    const int cb = t & 1, nb = cb ^ 1;
    // ===== phase 1: quadrant (m0-3, n0-1); stage (t+1, A-h0) =====
    #pragma unroll
    for (int mt = 0; mt < 4; ++mt) { af[mt][0] = LDA(cb, mt, 0); af[mt][1] = LDA(cb, mt, 1); }
    #pragma unroll
    for (int nt = 0; nt < 2; ++nt) { bf[nt][0] = LDB(cb, nt, 0); bf[nt][1] = LDB(cb, nt, 1); }
    if (t + 1 < 32) STGA(nb, t + 1, 0);
    __builtin_amdgcn_s_barrier();
    asm volatile("s_waitcnt lgkmcnt(0)" ::: "memory");
    __builtin_amdgcn_sched_barrier(0);
    MFMA_Q(0, 0);
    __builtin_amdgcn_s_barrier();
    // ===== phase 2: quadrant (m0-3, n2-3); stage (t+1, A-h1) =====
    #pragma unroll
    for (int nt = 2; nt < 4; ++nt) { bf[nt][0] = LDB(cb, nt, 0); bf[nt][1] = LDB(cb, nt, 1); }
    if (t + 1 < 32) STGA(nb, t + 1, 1);
    __builtin_amdgcn_s_barrier();
    asm volatile("s_waitcnt lgkmcnt(0)" ::: "memory");
    __builtin_amdgcn_sched_barrier(0);
    MFMA_Q(0, 2);
    __builtin_amdgcn_s_barrier();
    // ===== phase 3: quadrant (m4-7, n2-3); stage (t+2, B-h0) into cb =====
    #pragma unroll
    for (int mt = 0; mt < 4; ++mt) { af[mt][0] = LDA(cb, mt + 4, 0); af[mt][1] = LDA(cb, mt + 4, 1); }
    if (t + 2 < 32) STGB(cb, t + 2, 0);
    __builtin_amdgcn_s_barrier();
    asm volatile("s_waitcnt lgkmcnt(0)" ::: "memory");
    __builtin_amdgcn_sched_barrier(0);
    MFMA_Q(4, 2);
    __builtin_amdgcn_s_barrier();
    // ===== phase 4: quadrant (m4-7, n0-1); stage (t+2, B-h1); counted vmcnt =====
    if (t + 2 < 32) {
      STGB(cb, t + 2, 1);
      asm volatile("s_waitcnt vmcnt(4)" ::: "memory");  // retire all of tile t+1
    } else {
      asm volatile("s_waitcnt vmcnt(0)" ::: "memory");  // tail drain (t=30,31)
    }
    __builtin_amdgcn_s_barrier();
    MFMA_Q(4, 0);
    __builtin_amdgcn_s_barrier();
  }

  // ---- RoPE in-register for Q/K (pairs = adjacent lanes via DPP xor1) ----
  if (wsel < 2) {
    const float post = (wsel == 0) ? 0.1275174306f : 1.0f;  // log2(e)/sqrt(128)
    float fr[4];
    #pragma unroll
    for (int nt = 0; nt < 4; ++nt) {
      int pi = (wn & 1) * 32 + nt * 8 + (l16 >> 1);        // pair index 0..63
      fr[nt] = __expf(-0.14391156831f * (float)pi);        // theta^(-pi/64)
    }
    const float sgn = (l16 & 1) ? 1.0f : -1.0f;
    #pragma unroll
    for (int mt = 0; mt < 8; ++mt) {
      #pragma unroll
      for (int r = 0; r < 4; ++r) {
        int m = bm + wm*128 + mt*16 + quad*4 + r;
        float fp = (float)pos[m & 2047];
        #pragma unroll
        for (int nt = 0; nt < 4; ++nt) {
          float v = acc[mt][nt][r];
          float p = dppf<0xB1>(v);               // partner (d^1) value
          float ang = fp * fr[nt];
          float sn = __sinf(ang), cs = __cosf(ang);
          acc[mt][nt][r] = (v * cs + sgn * p * sn) * post;
        }
      }
    }
  }

  #pragma unroll
  for (int mt = 0; mt < 8; ++mt)
    #pragma unroll
    for (int nt = 0; nt < 4; ++nt)
      #pragma unroll
      for (int r = 0; r < 4; ++r) {
        int m = bm + wm*128 + mt*16 + quad*4 + r;
        int n = bn + wn*64 + nt*16 + l16;
        int b = m >> 11, s = m & 2047;
        int h = n >> 7,  d = n & 127;
        Cout[(((size_t)(b*HH + h)*SS + s)*DHH) + d] = f2b(acc[mt][nt][r]);
      }
}

// ---------------- O-projection GEMM (fp32 out, direct) ----------------
__global__ __launch_bounds__(256)
void gemm_o(const short* __restrict__ A, const short* __restrict__ Bw,
            float* __restrict__ Cout) {
  __shared__ __align__(16) short As[128*64];
  __shared__ __align__(16) short Bs[128*64];
  const int tid = threadIdx.x;
  const int lane = tid & 63;
  const int wave = tid >> 6;
  const int wm = wave >> 1, wn = wave & 1;
  const int quad = lane >> 4, l16 = lane & 15;
  const int bm = blockIdx.y * 128, bn = blockIdx.x * 128;
  const int K = DD;

  const int srow = tid >> 3;
  const int scol = (tid & 7) * 8;
  const short* aBase = A + (size_t)(bm + srow) * K + scol;
  const short* bBase = Bw + (size_t)(bn + srow) * K + scol;
  f32x4 acc[4][4] = {};

  for (int k0 = 0; k0 < K; k0 += 64) {
    #pragma unroll
    for (int j = 0; j < 4; ++j) {
      GLOAD_LDS16(aBase + (size_t)j * 32 * K + k0, As + j * 2048 + wave * 512);
      GLOAD_LDS16(bBase + (size_t)j * 32 * K + k0, Bs + j * 2048 + wave * 512);
    }
    __syncthreads();
    #pragma unroll
    for (int kk = 0; kk < 64; kk += 32) {
      bf16x8 af[4], bf[4];
      #pragma unroll
      for (int t = 0; t < 4; ++t)
        af[t] = *(const bf16x8*)&As[(wm*64 + t*16 + l16) * 64 + kk + quad*8];
      #pragma unroll
      for (int t = 0; t < 4; ++t)
        bf[t] = *(const bf16x8*)&Bs[(wn*64 + t*16 + l16) * 64 + kk + quad*8];
      #pragma unroll
      for (int mt = 0; mt < 4; ++mt)
        #pragma unroll
        for (int nt = 0; nt < 4; ++nt)
          acc[mt][nt] = __builtin_amdgcn_mfma_f32_16x16x32_bf16(af[mt], bf[nt], acc[mt][nt], 0, 0, 0);
    }
    __syncthreads();
  }

  #pragma unroll
  for (int mt = 0; mt < 4; ++mt)
    #pragma unroll
    for (int nt = 0; nt < 4; ++nt)
      #pragma unroll
      for (int r = 0; r < 4; ++r) {
        int m = bm + wm*64 + mt*16 + quad*4 + r;
        int n = bn + wn*64 + nt*16 + l16;
        Cout[(size_t)m * DD + n] = acc[mt][nt][r];
      }
}

// ---------------- Flash attention (causal), one 64-row Q tile per block ----------
// Q pre-scaled by log2(e)/sqrt(DH); softmax in exp2 domain.
// 256 threads (4 waves), each wave owns 16 q-rows; ALL waves active EVERY
// iteration (no paired-tile idling). 1024 blocks = 4 blocks/CU (LDS 40 KB).
// Grid mapping: linear = qslot*32 + bh; co-resident quads {s,s+8,s+16,s+24}
// (spacing 256 = XCD round-robin stride) map to q-tiles whose work sums to a
// constant 66 k-tile units, and share bh for K/V L2 reuse.
// T13 defer-rescale: skip o-rescale while tile max stays within 2^11.5.
__global__ __launch_bounds__(256, 4)
void attn(const short* __restrict__ Q, const short* __restrict__ K,
          const short* __restrict__ V, short* __restrict__ O) {
  __shared__ __align__(16) short Ks[64*128];    // [key][dim], swizzled rows (256 B)
  __shared__ __align__(16) short Vt[128*64];    // [dim][key], swizzled rows (128 B)
  __shared__ __align__(16) short Pb[4*16*64];   // per-wave P [16 q][64 k], swizzled
  const int tid = threadIdx.x;
  const int lane = tid & 63, wave = tid >> 6;   // wave 0..3
  const int quad = lane >> 4, l16 = lane & 15;
  const int L = blockIdx.x;
  const int bh = L & 31;
  const int s = L >> 5;                         // 0..31
  const int qt = (s < 8) ? 31 - s : (s < 16) ? s - 8 : (s < 24) ? 39 - s : s - 16;
  const int b = bh >> 4, h = bh & 15;
  const short* Kg = K + (size_t)bh * SS * DHH;
  const short* Vg = V + (size_t)bh * SS * DHH;

  const int qbase = qt * 64 + wave * 16;

  bf16x8 aq[4];
  {
    const short* qp = Q + ((size_t)bh * SS + qbase + l16) * DHH + quad*8;
    #pragma unroll
    for (int ks = 0; ks < 4; ++ks) aq[ks] = *(const bf16x8*)(qp + ks*32);
  }

  f32x4 o[8] = {};
  float mrow[4], lrow[4];
  #pragma unroll
  for (int r = 0; r < 4; ++r) { mrow[r] = -1e30f; lrow[r] = 0.f; }

  const int krow = tid >> 2;            // 0..63 key row
  const int kcolb = (tid & 3) * 64;     // byte col within 256 B key row
  const int vkp = (tid & 31) * 2;       // key pair
  const int vds = (tid >> 5) * 16;      // dim base (16 dims)

  const int nkt = qt + 1;
  int4 kreg[4], vreg[4];
  {
    const short* kp = Kg + (size_t)krow * DHH + (kcolb >> 1);
    #pragma unroll
    for (int j = 0; j < 4; ++j) kreg[j] = *(const int4*)(kp + j*8);
    const short* vp = Vg + (size_t)vkp * DHH + vds;
    vreg[0] = *(const int4*)vp;        vreg[1] = *(const int4*)(vp + 8);
    vreg[2] = *(const int4*)(vp + DHH); vreg[3] = *(const int4*)(vp + DHH + 8);
  }

  for (int kt = 0; kt < nkt; ++kt) {
    // ---- stage K (swizzled) ----
    #pragma unroll
    for (int j = 0; j < 4; ++j)
      *(int4*)((char*)Ks + krow*256 + ((kcolb + j*16) ^ ((krow & 7) << 4))) = kreg[j];
    // ---- stage V^T (transpose in-register, swizzled) ----
    {
      const short* s0 = (const short*)&vreg[0];   // key vkp,   dims vds..vds+15
      const short* s1 = (const short*)&vreg[2];   // key vkp+1, dims vds..vds+15
      #pragma unroll
      for (int e = 0; e < 16; ++e) {
        int dim = vds + e;
        int val = (int)(unsigned short)s0[e] | ((int)(unsigned short)s1[e] << 16);
        *(int*)((char*)Vt + dim*128 + ((vkp*2) ^ ((dim & 7) << 4))) = val;
      }
    }
    __syncthreads();

    // prefetch next tile into regs (hides HBM under compute)
    if (kt + 1 < nkt) {
      const short* kp = Kg + (size_t)((kt+1)*64 + krow) * DHH + (kcolb >> 1);
      #pragma unroll
      for (int j = 0; j < 4; ++j) kreg[j] = *(const int4*)(kp + j*8);
      const short* vp = Vg + (size_t)((kt+1)*64 + vkp) * DHH + vds;
      vreg[0] = *(const int4*)vp;        vreg[1] = *(const int4*)(vp + 8);
      vreg[2] = *(const int4*)(vp + DHH); vreg[3] = *(const int4*)(vp + DHH + 8);
    }

    // ---- QK^T: 16 queries x 64 keys ----
    float sv[4][4];
    __builtin_amdgcn_s_setprio(1);
    #pragma unroll
    for (int nt = 0; nt < 4; ++nt) {
      f32x4 a = {0.f, 0.f, 0.f, 0.f};
      #pragma unroll
      for (int ks = 0; ks < 4; ++ks) {
        int key = nt*16 + l16;
        bf16x8 bk = *(const bf16x8*)((const char*)Ks + key*256 +
                       ((ks*64 + quad*16) ^ ((key & 7) << 4)));
        a = __builtin_amdgcn_mfma_f32_16x16x32_bf16(aq[ks], bk, a, 0, 0, 0);
      }
      #pragma unroll
      for (int r = 0; r < 4; ++r) sv[nt][r] = a[r];
    }
    __builtin_amdgcn_s_setprio(0);

    // ---- causal mask on the diagonal tile ----
    if (kt == qt) {
      #pragma unroll
      for (int nt = 0; nt < 4; ++nt)
        #pragma unroll
        for (int r = 0; r < 4; ++r)
          if (nt*16 + l16 > wave*16 + quad*4 + r) sv[nt][r] = -1e30f;
    }

    // ---- online softmax (exp2 domain, defer-rescale THR=11.5) ----
    #pragma unroll
    for (int r = 0; r < 4; ++r) {
      float mx = fmaxf(fmaxf(sv[0][r], sv[1][r]), fmaxf(sv[2][r], sv[3][r]));
      mx = rmax16(mx);
      if (!__all(mx - mrow[r] <= 11.5f)) {
        float mnew = fmaxf(mrow[r], mx);
        float alpha = EXP2F(mrow[r] - mnew);
        lrow[r] *= alpha;
        #pragma unroll
        for (int nt = 0; nt < 8; ++nt) o[nt][r] *= alpha;
        mrow[r] = mnew;
      }
      float ls = 0.f;
      #pragma unroll
      for (int nt = 0; nt < 4; ++nt) {
        float pv = EXP2F(sv[nt][r] - mrow[r]);
        sv[nt][r] = pv; ls += pv;
      }
      ls = rsum16(ls);
      lrow[r] += ls;
    }

    // ---- P -> LDS (per-wave region, swizzled) ----
    #pragma unroll
    for (int nt = 0; nt < 4; ++nt)
      #pragma unroll
      for (int r = 0; r < 4; ++r) {
        int qr = quad*4 + r;
        *(short*)((char*)Pb + wave*2048 + qr*128 +
                  (((nt*16 + l16)*2) ^ ((qr & 7) << 4))) = f2b_fast(sv[nt][r]);
      }

    bf16x8 ap[2];
    #pragma unroll
    for (int k2 = 0; k2 < 2; ++k2)
      ap[k2] = *(const bf16x8*)((const char*)Pb + wave*2048 + l16*128 +
                  ((k2*64 + quad*16) ^ ((l16 & 7) << 4)));

    // ---- PV ----
    __builtin_amdgcn_s_setprio(1);
    #pragma unroll
    for (int k2 = 0; k2 < 2; ++k2)
      #pragma unroll
      for (int nt = 0; nt < 8; ++nt) {
        int d = nt*16 + l16;
        bf16x8 bv = *(const bf16x8*)((const char*)Vt + d*128 +
                       ((k2*64 + quad*16) ^ ((d & 7) << 4)));
        o[nt] = __builtin_amdgcn_mfma_f32_16x16x32_bf16(ap[k2], bv, o[nt], 0, 0, 0);
      }
    __builtin_amdgcn_s_setprio(0);

    __syncthreads();
  }

  #pragma unroll
  for (int nt = 0; nt < 8; ++nt)
    #pragma unroll
    for (int r = 0; r < 4; ++r) {
      int q = qbase + quad*4 + r;
      float v = o[nt][r] / lrow[r];
      O[((size_t)(b*SS + q)) * DD + h*DHH + nt*16 + l16] = f2b(v);
    }
}

extern "C" void kernel_launch(void* const* d_in, const int* in_sizes, int n_in,
                              void* d_out, int out_size, void* d_ws, size_t ws_size,
                              hipStream_t stream) {
  const float* x  = (const float*)d_in[0];
  const int* pos  = (const int*)d_in[1];
  const float* Wq = (const float*)d_in[2];
  const float* Wk = (const float*)d_in[3];
  const float* Wv = (const float*)d_in[4];
  const float* Wo = (const float*)d_in[5];

  char* ws = (char*)d_ws;
  short* xb  = (short*)(ws);
  short* wqb = (short*)(ws + 16777216);
  short* wkb = (short*)(ws + 25165824);
  short* wvb = (short*)(ws + 33554432);
  short* wob = (short*)(ws + 41943040);
  short* Qb  = (short*)(ws + 50331648);
  short* Kb  = (short*)(ws + 67108864);
  short* Vb  = (short*)(ws + 83886080);
  short* Ob  = (short*)(ws + 100663296);

  cvt_all<<<24576, 256, 0, stream>>>(x, Wq, Wk, Wv, Wo, xb, wqb, wkb, wvb, wob);

  dim3 gq(24, MM/256);       // fused QKV: 384 blocks, 256x256 tiles, 8-phase
  gemm_qkv<<<gq, 512, 0, stream>>>(xb, wqb, wkb, wvb, pos, Qb, Kb, Vb);

  attn<<<1024, 256, 0, stream>>>(Qb, Kb, Vb, Ob);   // 4 blocks/CU, balanced quads

  dim3 go(DD/128, MM/128);   // 512 blocks, direct fp32 out
  gemm_o<<<go, 256, 0, stream>>>(Ob, wob, (float*)d_out);
}

// Round 4
// 398.831 us; speedup vs baseline: 2.4406x; 2.4406x over previous
//
#include <hip/hip_runtime.h>
#include <hip/hip_bf16.h>
#include <math.h>

#define BB 2
#define SS 2048
#define DD 2048
#define HH 16
#define DHH 128
#define MM (BB*SS)   // 4096

typedef __attribute__((ext_vector_type(8))) short bf16x8;
typedef __attribute__((ext_vector_type(4))) float f32x4;

#define AS1 __attribute__((address_space(1)))
#define AS3 __attribute__((address_space(3)))
#define GLOAD_LDS16(g, l) __builtin_amdgcn_global_load_lds((const AS1 void*)(g), (AS3 void*)(l), 16, 0, 0)

#if __has_builtin(__builtin_amdgcn_exp2f)
#define EXP2F(x) __builtin_amdgcn_exp2f(x)
#else
#define EXP2F(x) exp2f(x)
#endif

__device__ __forceinline__ float b2f(short s) {
  union { unsigned int u; float f; } v;
  v.u = ((unsigned int)(unsigned short)s) << 16;
  return v.f;
}
__device__ __forceinline__ short f2b(float f) {
  union { float f; unsigned int u; } v; v.f = f;
  unsigned int u = v.u;
  u += 0x7fffu + ((u >> 16) & 1u);   // round-to-nearest-even
  return (short)(u >> 16);
}
// fast round-half-up; valid for non-negative finite values
__device__ __forceinline__ short f2b_fast(float f) {
  union { float f; unsigned int u; } v; v.f = f;
  return (short)((v.u + 0x8000u) >> 16);
}

// ---- DPP helpers (VALU pipe, no LDS ops) ----
template<int CTRL>
__device__ __forceinline__ float dppf(float x) {
  int xi = __builtin_bit_cast(int, x);
  int r = __builtin_amdgcn_update_dpp(0, xi, CTRL, 0xf, 0xf, true);
  return __builtin_bit_cast(float, r);
}
__device__ __forceinline__ float rmax16(float x) {
  x = fmaxf(x, dppf<0xB1>(x));   // quad_perm xor1
  x = fmaxf(x, dppf<0x4E>(x));   // quad_perm xor2
  x = fmaxf(x, dppf<0x141>(x));  // row_half_mirror
  x = fmaxf(x, dppf<0x140>(x));  // row_mirror
  return x;
}
__device__ __forceinline__ float rsum16(float x) {
  x += dppf<0xB1>(x);
  x += dppf<0x4E>(x);
  x += dppf<0x141>(x);
  x += dppf<0x140>(x);
  return x;
}

// ---------------- fp32 -> bf16 convert, all 5 tensors in one launch ----------------
__global__ void cvt_all(const float* __restrict__ x,  const float* __restrict__ wq,
                        const float* __restrict__ wk, const float* __restrict__ wv,
                        const float* __restrict__ wo,
                        short* __restrict__ xb,  short* __restrict__ wqb,
                        short* __restrict__ wkb, short* __restrict__ wvb,
                        short* __restrict__ wob) {
  int i = blockIdx.x * blockDim.x + threadIdx.x;   // float4 index
  const float* src; short* dst; int off;
  if (i < 2097152) { src = x; dst = xb; off = i; }
  else {
    int j = i - 2097152;
    int w = j >> 20; off = j & 1048575;
    src = (w == 0) ? wq : (w == 1) ? wk : (w == 2) ? wv : wo;
    dst = (w == 0) ? wqb : (w == 1) ? wkb : (w == 2) ? wvb : wob;
  }
  float4 v = ((const float4*)src)[i < 2097152 ? off : off];
  short4 o;
  o.x = f2b(v.x); o.y = f2b(v.y); o.z = f2b(v.z); o.w = f2b(v.w);
  ((short4*)dst)[off] = o;
}

// ---------------- Fused QKV GEMM: 256x256 tile, 8-phase schedule -----------------
#define LDA(cb, mt, kk) (*(const bf16x8*)((const char*)smA + (cb)*32768 + \
    (wm*128 + (mt)*16 + l16)*128 + (((kk)*64 + quad*16) ^ ((l16 & 7) << 4))))
#define LDB(cb, nt, kk) (*(const bf16x8*)((const char*)smB + (cb)*32768 + \
    (wn*64 + (nt)*16 + l16)*128 + (((kk)*64 + quad*16) ^ ((l16 & 7) << 4))))
#define STGA(b, t, h) do { \
    GLOAD_LDS16(aBase + (size_t)((h)*128) * DD + (t)*64,      smA + (b)*16384 + ((h)*128)*64 + wst); \
    GLOAD_LDS16(aBase + (size_t)((h)*128 + 64) * DD + (t)*64, smA + (b)*16384 + ((h)*128 + 64)*64 + wst); } while(0)
#define STGB(b, t, h) do { \
    GLOAD_LDS16(bBase + (size_t)((h)*128) * DD + (t)*64,      smB + (b)*16384 + ((h)*128)*64 + wst); \
    GLOAD_LDS16(bBase + (size_t)((h)*128 + 64) * DD + (t)*64, smB + (b)*16384 + ((h)*128 + 64)*64 + wst); } while(0)
#define MFMA_Q(MT0, NT0) do { \
    __builtin_amdgcn_s_setprio(1); \
    _Pragma("unroll") \
    for (int mt = 0; mt < 4; ++mt) \
      _Pragma("unroll") \
      for (int nt = 0; nt < 2; ++nt) \
        _Pragma("unroll") \
        for (int kk = 0; kk < 2; ++kk) \
          acc[(MT0) + mt][(NT0) + nt] = __builtin_amdgcn_mfma_f32_16x16x32_bf16( \
              af[mt][kk], bf[(NT0) + nt][kk], acc[(MT0) + mt][(NT0) + nt], 0, 0, 0); \
    __builtin_amdgcn_s_setprio(0); } while(0)

__global__ __launch_bounds__(512, 2)
void gemm_qkv(const short* __restrict__ A,
              const short* __restrict__ Wq, const short* __restrict__ Wk,
              const short* __restrict__ Wv, const int* __restrict__ pos,
              short* __restrict__ Qo, short* __restrict__ Ko, short* __restrict__ Vo) {
  __shared__ __align__(16) short sm[65536];   // 128 KiB: A[2][256][64] | B[2][256][64]
  const int tid = threadIdx.x;
  const int lane = tid & 63;
  const int wave = tid >> 6;                  // 0..7
  const int quad = lane >> 4, l16 = lane & 15;
  const int wm = wave >> 2, wn = wave & 3;    // wave tile: 128 rows x 64 cols
  const int wsel = blockIdx.x >> 3;           // 0=Q 1=K 2=V
  const short* Bw = (wsel == 0) ? Wq : (wsel == 1) ? Wk : Wv;
  short* Cout = (wsel == 0) ? Qo : (wsel == 1) ? Ko : Vo;
  const int bn = (blockIdx.x & 7) * 256;
  const int bm = blockIdx.y * 256;

  short* smA = sm;                 // bufs at +0, +16384 (shorts)
  short* smB = sm + 32768;         // bufs at +0, +16384 (shorts)
  const int wst = wave * 512;      // wave's staging base (8 rows x 64 shorts)

  const int srow = tid >> 3;                          // 0..63
  const int scol = ((tid & 7) ^ (srow & 7)) * 8;      // shorts, pre-swizzled
  const short* aBase = A  + (size_t)(bm + srow) * DD + scol;
  const short* bBase = Bw + (size_t)(bn + srow) * DD + scol;

  f32x4 acc[8][4] = {};
  bf16x8 af[4][2], bf[4][2];

  // ---- prologue: tile0 (A+B) + tile1 (B); leave tile1's B in flight ----
  STGA(0, 0, 0); STGA(0, 0, 1);
  STGB(0, 0, 0); STGB(0, 0, 1);
  STGB(1, 1, 0); STGB(1, 1, 1);
  asm volatile("s_waitcnt vmcnt(4)" ::: "memory");   // tile0 fully resident
  __builtin_amdgcn_s_barrier();

  for (int t = 0; t < 32; ++t) {
    const int cb = t & 1, nb = cb ^ 1;
    // ===== phase 1: quadrant (m0-3, n0-1); stage (t+1, A-h0) =====
    #pragma unroll
    for (int mt = 0; mt < 4; ++mt) { af[mt][0] = LDA(cb, mt, 0); af[mt][1] = LDA(cb, mt, 1); }
    #pragma unroll
    for (int nt = 0; nt < 2; ++nt) { bf[nt][0] = LDB(cb, nt, 0); bf[nt][1] = LDB(cb, nt, 1); }
    if (t + 1 < 32) STGA(nb, t + 1, 0);
    __builtin_amdgcn_s_barrier();
    asm volatile("s_waitcnt lgkmcnt(0)" ::: "memory");
    __builtin_amdgcn_sched_barrier(0);
    MFMA_Q(0, 0);
    __builtin_amdgcn_s_barrier();
    // ===== phase 2: quadrant (m0-3, n2-3); stage (t+1, A-h1) =====
    #pragma unroll
    for (int nt = 2; nt < 4; ++nt) { bf[nt][0] = LDB(cb, nt, 0); bf[nt][1] = LDB(cb, nt, 1); }
    if (t + 1 < 32) STGA(nb, t + 1, 1);
    __builtin_amdgcn_s_barrier();
    asm volatile("s_waitcnt lgkmcnt(0)" ::: "memory");
    __builtin_amdgcn_sched_barrier(0);
    MFMA_Q(0, 2);
    __builtin_amdgcn_s_barrier();
    // ===== phase 3: quadrant (m4-7, n2-3); stage (t+2, B-h0) into cb =====
    #pragma unroll
    for (int mt = 0; mt < 4; ++mt) { af[mt][0] = LDA(cb, mt + 4, 0); af[mt][1] = LDA(cb, mt + 4, 1); }
    if (t + 2 < 32) STGB(cb, t + 2, 0);
    __builtin_amdgcn_s_barrier();
    asm volatile("s_waitcnt lgkmcnt(0)" ::: "memory");
    __builtin_amdgcn_sched_barrier(0);
    MFMA_Q(4, 2);
    __builtin_amdgcn_s_barrier();
    // ===== phase 4: quadrant (m4-7, n0-1); stage (t+2, B-h1); counted vmcnt =====
    if (t + 2 < 32) {
      STGB(cb, t + 2, 1);
      asm volatile("s_waitcnt vmcnt(4)" ::: "memory");  // retire all of tile t+1
    } else {
      asm volatile("s_waitcnt vmcnt(0)" ::: "memory");  // tail drain (t=30,31)
    }
    __builtin_amdgcn_s_barrier();
    MFMA_Q(4, 0);
    __builtin_amdgcn_s_barrier();
  }

  // ---- RoPE in-register for Q/K (pairs = adjacent lanes via DPP xor1) ----
  if (wsel < 2) {
    const float post = (wsel == 0) ? 0.1275174306f : 1.0f;  // log2(e)/sqrt(128)
    float fr[4];
    #pragma unroll
    for (int nt = 0; nt < 4; ++nt) {
      int pi = (wn & 1) * 32 + nt * 8 + (l16 >> 1);        // pair index 0..63
      fr[nt] = __expf(-0.14391156831f * (float)pi);        // theta^(-pi/64)
    }
    const float sgn = (l16 & 1) ? 1.0f : -1.0f;
    #pragma unroll
    for (int mt = 0; mt < 8; ++mt) {
      #pragma unroll
      for (int r = 0; r < 4; ++r) {
        int m = bm + wm*128 + mt*16 + quad*4 + r;
        float fp = (float)pos[m & 2047];
        #pragma unroll
        for (int nt = 0; nt < 4; ++nt) {
          float v = acc[mt][nt][r];
          float p = dppf<0xB1>(v);               // partner (d^1) value
          float ang = fp * fr[nt];
          float sn = __sinf(ang), cs = __cosf(ang);
          acc[mt][nt][r] = (v * cs + sgn * p * sn) * post;
        }
      }
    }
  }

  #pragma unroll
  for (int mt = 0; mt < 8; ++mt)
    #pragma unroll
    for (int nt = 0; nt < 4; ++nt)
      #pragma unroll
      for (int r = 0; r < 4; ++r) {
        int m = bm + wm*128 + mt*16 + quad*4 + r;
        int n = bn + wn*64 + nt*16 + l16;
        int b = m >> 11, s = m & 2047;
        int h = n >> 7,  d = n & 127;
        Cout[(((size_t)(b*HH + h)*SS + s)*DHH) + d] = f2b(acc[mt][nt][r]);
      }
}

// ---------------- O-projection GEMM (fp32 out, direct) ----------------
__global__ __launch_bounds__(256)
void gemm_o(const short* __restrict__ A, const short* __restrict__ Bw,
            float* __restrict__ Cout) {
  __shared__ __align__(16) short As[128*64];
  __shared__ __align__(16) short Bs[128*64];
  const int tid = threadIdx.x;
  const int lane = tid & 63;
  const int wave = tid >> 6;
  const int wm = wave >> 1, wn = wave & 1;
  const int quad = lane >> 4, l16 = lane & 15;
  const int bm = blockIdx.y * 128, bn = blockIdx.x * 128;
  const int K = DD;

  const int srow = tid >> 3;
  const int scol = (tid & 7) * 8;
  const short* aBase = A + (size_t)(bm + srow) * K + scol;
  const short* bBase = Bw + (size_t)(bn + srow) * K + scol;
  f32x4 acc[4][4] = {};

  for (int k0 = 0; k0 < K; k0 += 64) {
    #pragma unroll
    for (int j = 0; j < 4; ++j) {
      GLOAD_LDS16(aBase + (size_t)j * 32 * K + k0, As + j * 2048 + wave * 512);
      GLOAD_LDS16(bBase + (size_t)j * 32 * K + k0, Bs + j * 2048 + wave * 512);
    }
    __syncthreads();
    #pragma unroll
    for (int kk = 0; kk < 64; kk += 32) {
      bf16x8 af[4], bf[4];
      #pragma unroll
      for (int t = 0; t < 4; ++t)
        af[t] = *(const bf16x8*)&As[(wm*64 + t*16 + l16) * 64 + kk + quad*8];
      #pragma unroll
      for (int t = 0; t < 4; ++t)
        bf[t] = *(const bf16x8*)&Bs[(wn*64 + t*16 + l16) * 64 + kk + quad*8];
      #pragma unroll
      for (int mt = 0; mt < 4; ++mt)
        #pragma unroll
        for (int nt = 0; nt < 4; ++nt)
          acc[mt][nt] = __builtin_amdgcn_mfma_f32_16x16x32_bf16(af[mt], bf[nt], acc[mt][nt], 0, 0, 0);
    }
    __syncthreads();
  }

  #pragma unroll
  for (int mt = 0; mt < 4; ++mt)
    #pragma unroll
    for (int nt = 0; nt < 4; ++nt)
      #pragma unroll
      for (int r = 0; r < 4; ++r) {
        int m = bm + wm*64 + mt*16 + quad*4 + r;
        int n = bn + wn*64 + nt*16 + l16;
        Cout[(size_t)m * DD + n] = acc[mt][nt][r];
      }
}

// ---------------- Flash attention (causal), one 64-row Q tile per block ----------
// 256 threads (4 waves); all waves active every iteration. Balanced grid:
// co-resident quads {s,s+8,s+16,s+24} sum to 66 k-tile units, same bh.
// Spill-free design: K staged via global_load_lds (pre-swizzled source, no kreg);
// V reg-prefetch (16 VGPR) with counted vmcnt(4) kept in flight across barrier;
// plain online softmax (exp2 domain). launch_bounds(256,3): no forced spill.
__global__ __launch_bounds__(256, 3)
void attn(const short* __restrict__ Q, const short* __restrict__ K,
          const short* __restrict__ V, short* __restrict__ O) {
  __shared__ __align__(16) short Ks[64*128];    // 16 KB [key][dim], swizzled
  __shared__ __align__(16) short Vt[128*64];    // 16 KB [dim][key], swizzled
  __shared__ __align__(16) short Pb[4*16*64];   // 8 KB per-wave P, swizzled
  const int tid = threadIdx.x;
  const int lane = tid & 63, wave = tid >> 6;   // wave 0..3
  const int quad = lane >> 4, l16 = lane & 15;
  const int L = blockIdx.x;
  const int bh = L & 31;
  const int s = L >> 5;                         // 0..31
  const int qt = (s < 8) ? 31 - s : (s < 16) ? s - 8 : (s < 24) ? 39 - s : s - 16;
  const int b = bh >> 4, h = bh & 15;
  const short* Kg = K + (size_t)bh * SS * DHH;
  const short* Vg = V + (size_t)bh * SS * DHH;
  const int qbase = qt * 64 + wave * 16;

  bf16x8 aq[4];
  {
    const short* qp = Q + ((size_t)bh * SS + qbase + l16) * DHH + quad*8;
    #pragma unroll
    for (int ks = 0; ks < 4; ++ks) aq[ks] = *(const bf16x8*)(qp + ks*32);
  }

  f32x4 o[8] = {};
  float mrow[4], lrow[4];
  #pragma unroll
  for (int r = 0; r < 4; ++r) { mrow[r] = -1e30f; lrow[r] = 0.f; }

  // K staging geometry: LDS linear (wave,j,lane) -> key = wave*16+j*4+(lane>>4),
  // colb = (lane&15)*16; global source col pre-swizzled (both-sides rule).
  const int skey0 = wave*16 + (lane >> 4);
  const int scolb = (lane & 15) << 4;
  // V staging geometry (reg transpose)
  const int vkp = (tid & 31) * 2;
  const int vds = (tid >> 5) * 16;

  const int nkt = qt + 1;
  int4 vreg[4];
  {
    const short* vp = Vg + (size_t)vkp * DHH + vds;
    vreg[0] = *(const int4*)vp;         vreg[1] = *(const int4*)(vp + 8);
    vreg[2] = *(const int4*)(vp + DHH); vreg[3] = *(const int4*)(vp + DHH + 8);
  }

  for (int kt = 0; kt < nkt; ++kt) {
    // ---- stage K(kt) direct to LDS (async, 4 x 1KB/wave) ----
    {
      const short* Kt = Kg + (size_t)kt * 64 * DHH;
      #pragma unroll
      for (int j = 0; j < 4; ++j) {
        int key = skey0 + j*4;
        GLOAD_LDS16(Kt + (size_t)key * DHH + ((scolb ^ ((key & 7) << 4)) >> 1),
                    Ks + wave*2048 + j*512);
      }
    }
    asm volatile("" ::: "memory");   // pin: V loads must issue AFTER K gloads
    // ---- V(kt): transpose-write from regs, swizzled ----
    {
      const short* s0 = (const short*)&vreg[0];   // key vkp,   dims vds..+15
      const short* s1 = (const short*)&vreg[2];   // key vkp+1, dims vds..+15
      #pragma unroll
      for (int e = 0; e < 16; ++e) {
        int dim = vds + e;
        int val = (int)(unsigned short)s0[e] | ((int)(unsigned short)s1[e] << 16);
        *(int*)((char*)Vt + dim*128 + ((vkp*2) ^ ((dim & 7) << 4))) = val;
      }
    }
    // ---- prefetch V(kt+1) into regs; counted wait keeps it in flight ----
    if (kt + 1 < nkt) {
      const short* vp = Vg + (size_t)((kt+1)*64 + vkp) * DHH + vds;
      vreg[0] = *(const int4*)vp;         vreg[1] = *(const int4*)(vp + 8);
      vreg[2] = *(const int4*)(vp + DHH); vreg[3] = *(const int4*)(vp + DHH + 8);
      asm volatile("s_waitcnt vmcnt(4) lgkmcnt(0)" ::: "memory");  // K done, V in flight
    } else {
      asm volatile("s_waitcnt vmcnt(0) lgkmcnt(0)" ::: "memory");
    }
    __builtin_amdgcn_s_barrier();
    __builtin_amdgcn_sched_barrier(0);

    // ---- QK^T: 16 queries x 64 keys ----
    float sv[4][4];
    __builtin_amdgcn_s_setprio(1);
    #pragma unroll
    for (int nt = 0; nt < 4; ++nt) {
      f32x4 a = {0.f, 0.f, 0.f, 0.f};
      #pragma unroll
      for (int ks = 0; ks < 4; ++ks) {
        int key = nt*16 + l16;
        bf16x8 bk = *(const bf16x8*)((const char*)Ks + key*256 +
                       ((ks*64 + quad*16) ^ ((key & 7) << 4)));
        a = __builtin_amdgcn_mfma_f32_16x16x32_bf16(aq[ks], bk, a, 0, 0, 0);
      }
      #pragma unroll
      for (int r = 0; r < 4; ++r) sv[nt][r] = a[r];
    }
    __builtin_amdgcn_s_setprio(0);

    // ---- causal mask on the diagonal tile ----
    if (kt == qt) {
      #pragma unroll
      for (int nt = 0; nt < 4; ++nt)
        #pragma unroll
        for (int r = 0; r < 4; ++r)
          if (nt*16 + l16 > wave*16 + quad*4 + r) sv[nt][r] = -1e30f;
    }

    // ---- online softmax (exp2 domain, plain rescale) ----
    #pragma unroll
    for (int r = 0; r < 4; ++r) {
      float mx = fmaxf(fmaxf(sv[0][r], sv[1][r]), fmaxf(sv[2][r], sv[3][r]));
      mx = rmax16(mx);
      float mnew = fmaxf(mrow[r], mx);
      float alpha = EXP2F(mrow[r] - mnew);
      float ls = 0.f;
      #pragma unroll
      for (int nt = 0; nt < 4; ++nt) {
        float pv = EXP2F(sv[nt][r] - mnew);
        sv[nt][r] = pv; ls += pv;
      }
      ls = rsum16(ls);
      lrow[r] = lrow[r] * alpha + ls;
      mrow[r] = mnew;
      #pragma unroll
      for (int nt = 0; nt < 8; ++nt) o[nt][r] *= alpha;
    }

    // ---- P -> LDS (per-wave region, swizzled) ----
    #pragma unroll
    for (int nt = 0; nt < 4; ++nt)
      #pragma unroll
      for (int r = 0; r < 4; ++r) {
        int qr = quad*4 + r;
        *(short*)((char*)Pb + wave*2048 + qr*128 +
                  (((nt*16 + l16)*2) ^ ((qr & 7) << 4))) = f2b_fast(sv[nt][r]);
      }

    bf16x8 ap[2];
    #pragma unroll
    for (int k2 = 0; k2 < 2; ++k2)
      ap[k2] = *(const bf16x8*)((const char*)Pb + wave*2048 + l16*128 +
                  ((k2*64 + quad*16) ^ ((l16 & 7) << 4)));

    // ---- PV ----
    __builtin_amdgcn_s_setprio(1);
    #pragma unroll
    for (int k2 = 0; k2 < 2; ++k2)
      #pragma unroll
      for (int nt = 0; nt < 8; ++nt) {
        int d = nt*16 + l16;
        bf16x8 bv = *(const bf16x8*)((const char*)Vt + d*128 +
                       ((k2*64 + quad*16) ^ ((d & 7) << 4)));
        o[nt] = __builtin_amdgcn_mfma_f32_16x16x32_bf16(ap[k2], bv, o[nt], 0, 0, 0);
      }
    __builtin_amdgcn_s_setprio(0);

    // ---- end of iter: LDS reads drained; V prefetch stays in flight ----
    asm volatile("s_waitcnt lgkmcnt(0)" ::: "memory");
    __builtin_amdgcn_s_barrier();
    __builtin_amdgcn_sched_barrier(0);
  }

  #pragma unroll
  for (int nt = 0; nt < 8; ++nt)
    #pragma unroll
    for (int r = 0; r < 4; ++r) {
      int q = qbase + quad*4 + r;
      float v = o[nt][r] / lrow[r];
      O[((size_t)(b*SS + q)) * DD + h*DHH + nt*16 + l16] = f2b(v);
    }
}

extern "C" void kernel_launch(void* const* d_in, const int* in_sizes, int n_in,
                              void* d_out, int out_size, void* d_ws, size_t ws_size,
                              hipStream_t stream) {
  const float* x  = (const float*)d_in[0];
  const int* pos  = (const int*)d_in[1];
  const float* Wq = (const float*)d_in[2];
  const float* Wk = (const float*)d_in[3];
  const float* Wv = (const float*)d_in[4];
  const float* Wo = (const float*)d_in[5];

  char* ws = (char*)d_ws;
  short* xb  = (short*)(ws);
  short* wqb = (short*)(ws + 16777216);
  short* wkb = (short*)(ws + 25165824);
  short* wvb = (short*)(ws + 33554432);
  short* wob = (short*)(ws + 41943040);
  short* Qb  = (short*)(ws + 50331648);
  short* Kb  = (short*)(ws + 67108864);
  short* Vb  = (short*)(ws + 83886080);
  short* Ob  = (short*)(ws + 100663296);

  cvt_all<<<24576, 256, 0, stream>>>(x, Wq, Wk, Wv, Wo, xb, wqb, wkb, wvb, wob);

  dim3 gq(24, MM/256);       // fused QKV: 384 blocks, 256x256 tiles, 8-phase
  gemm_qkv<<<gq, 512, 0, stream>>>(xb, wqb, wkb, wvb, pos, Qb, Kb, Vb);

  attn<<<1024, 256, 0, stream>>>(Qb, Kb, Vb, Ob);   // balanced quads, 40 KB LDS

  dim3 go(DD/128, MM/128);   // 512 blocks, direct fp32 out
  gemm_o<<<go, 256, 0, stream>>>(Ob, wob, (float*)d_out);
}

// Round 5
// 380.492 us; speedup vs baseline: 2.5582x; 1.0482x over previous
//
#include <hip/hip_runtime.h>
#include <hip/hip_bf16.h>
#include <math.h>

#define BB 2
#define SS 2048
#define DD 2048
#define HH 16
#define DHH 128
#define MM (BB*SS)   // 4096

typedef __attribute__((ext_vector_type(8))) short bf16x8;
typedef __attribute__((ext_vector_type(4))) float f32x4;

#define AS1 __attribute__((address_space(1)))
#define AS3 __attribute__((address_space(3)))
#define GLOAD_LDS16(g, l) __builtin_amdgcn_global_load_lds((const AS1 void*)(g), (AS3 void*)(l), 16, 0, 0)

#if __has_builtin(__builtin_amdgcn_exp2f)
#define EXP2F(x) __builtin_amdgcn_exp2f(x)
#else
#define EXP2F(x) exp2f(x)
#endif

__device__ __forceinline__ float b2f(short s) {
  union { unsigned int u; float f; } v;
  v.u = ((unsigned int)(unsigned short)s) << 16;
  return v.f;
}
__device__ __forceinline__ short f2b(float f) {
  union { float f; unsigned int u; } v; v.f = f;
  unsigned int u = v.u;
  u += 0x7fffu + ((u >> 16) & 1u);   // round-to-nearest-even
  return (short)(u >> 16);
}
// fast round-half-up; valid for non-negative finite values
__device__ __forceinline__ short f2b_fast(float f) {
  union { float f; unsigned int u; } v; v.f = f;
  return (short)((v.u + 0x8000u) >> 16);
}

// ---- DPP helpers (VALU pipe, no LDS ops) ----
template<int CTRL>
__device__ __forceinline__ float dppf(float x) {
  int xi = __builtin_bit_cast(int, x);
  int r = __builtin_amdgcn_update_dpp(0, xi, CTRL, 0xf, 0xf, true);
  return __builtin_bit_cast(float, r);
}
__device__ __forceinline__ float rmax16(float x) {
  x = fmaxf(x, dppf<0xB1>(x));   // quad_perm xor1
  x = fmaxf(x, dppf<0x4E>(x));   // quad_perm xor2
  x = fmaxf(x, dppf<0x141>(x));  // row_half_mirror
  x = fmaxf(x, dppf<0x140>(x));  // row_mirror
  return x;
}
__device__ __forceinline__ float rsum16(float x) {
  x += dppf<0xB1>(x);
  x += dppf<0x4E>(x);
  x += dppf<0x141>(x);
  x += dppf<0x140>(x);
  return x;
}

// ---------------- fp32 -> bf16 convert, all 5 tensors in one launch ----------------
__global__ void cvt_all(const float* __restrict__ x,  const float* __restrict__ wq,
                        const float* __restrict__ wk, const float* __restrict__ wv,
                        const float* __restrict__ wo,
                        short* __restrict__ xb,  short* __restrict__ wqb,
                        short* __restrict__ wkb, short* __restrict__ wvb,
                        short* __restrict__ wob) {
  int i = blockIdx.x * blockDim.x + threadIdx.x;   // float4 index
  const float* src; short* dst; int off;
  if (i < 2097152) { src = x; dst = xb; off = i; }
  else {
    int j = i - 2097152;
    int w = j >> 20; off = j & 1048575;
    src = (w == 0) ? wq : (w == 1) ? wk : (w == 2) ? wv : wo;
    dst = (w == 0) ? wqb : (w == 1) ? wkb : (w == 2) ? wvb : wob;
  }
  float4 v = ((const float4*)src)[i < 2097152 ? off : off];
  short4 o;
  o.x = f2b(v.x); o.y = f2b(v.y); o.z = f2b(v.z); o.w = f2b(v.w);
  ((short4*)dst)[off] = o;
}

// =============== 256x128-tile 8-wave GEMM template (2-phase, counted vmcnt) ======
// 8 waves as 4M x 2N (wave tile 64x64), BK=64. LDS: A dbuf 64K + B tribuf 48K.
// T2 swizzle via pre-swizzled global source (global_load_lds writes linearly).
// Per K-tile: P1 {ds_read A(all)+B(n01), stage A(t+1), bar, lgkm, 16 MFMA, bar}
//             P2 {ds_read B(n23), stage B(t+2)->tribuf, vmcnt(2), bar, lgkm, 16 MFMA, bar}
// Steady-state queue at P2 wait: [B(t+1):2, A(t+1):4, B(t+2):2] -> vmcnt(2)
// retires exactly tile t+1; B(t+2) stays in flight. Tri-buffer B kills the WAR
// (stage target (t+2)%3 == (t-1)%3, whose readers drained a full tile ago).
#define LDA2(cb, mt, kk) (*(const bf16x8*)((const char*)smA + (cb)*32768 + \
    (wm*64 + (mt)*16 + l16)*128 + ((((kk)*64) + quad*16) ^ ((l16 & 7) << 4))))
#define LDB3(b, nt, kk) (*(const bf16x8*)((const char*)smB + (b)*16384 + \
    (wn*64 + (nt)*16 + l16)*128 + ((((kk)*64) + quad*16) ^ ((l16 & 7) << 4))))
#define STGA4(b, t) do { \
    _Pragma("unroll") \
    for (int h = 0; h < 4; ++h) \
      GLOAD_LDS16(aBase + (size_t)(h*64) * DD + (t)*64, smA + (b)*16384 + h*4096 + wst); } while(0)
#define STGB2M(b, t) do { \
    _Pragma("unroll") \
    for (int h = 0; h < 2; ++h) \
      GLOAD_LDS16(bBase + (size_t)(h*64) * DD + (t)*64, smB + (b)*8192 + h*4096 + wst); } while(0)
#define MFMA_P(NT0) do { \
    __builtin_amdgcn_s_setprio(1); \
    _Pragma("unroll") \
    for (int mt = 0; mt < 4; ++mt) \
      _Pragma("unroll") \
      for (int nt = 0; nt < 2; ++nt) \
        _Pragma("unroll") \
        for (int kk = 0; kk < 2; ++kk) \
          acc[mt][(NT0) + nt] = __builtin_amdgcn_mfma_f32_16x16x32_bf16( \
              af[mt][kk], bf[(NT0) + nt][kk], acc[mt][(NT0) + nt], 0, 0, 0); \
    __builtin_amdgcn_s_setprio(0); } while(0)

#define GEMM_KLOOP \
  STGA4(0, 0); STGB2M(0, 0); STGB2M(1, 1); \
  asm volatile("s_waitcnt vmcnt(2)" ::: "memory"); \
  __builtin_amdgcn_s_barrier(); \
  int b3 = 0, b3n2 = 2; \
  for (int t = 0; t < 32; ++t) { \
    const int cb = t & 1, nb = cb ^ 1; \
    _Pragma("unroll") \
    for (int mt = 0; mt < 4; ++mt) { af[mt][0] = LDA2(cb, mt, 0); af[mt][1] = LDA2(cb, mt, 1); } \
    _Pragma("unroll") \
    for (int nt = 0; nt < 2; ++nt) { bf[nt][0] = LDB3(b3, nt, 0); bf[nt][1] = LDB3(b3, nt, 1); } \
    if (t + 1 < 32) STGA4(nb, t + 1); \
    __builtin_amdgcn_s_barrier(); \
    asm volatile("s_waitcnt lgkmcnt(0)" ::: "memory"); \
    __builtin_amdgcn_sched_barrier(0); \
    MFMA_P(0); \
    __builtin_amdgcn_s_barrier(); \
    _Pragma("unroll") \
    for (int nt = 2; nt < 4; ++nt) { bf[nt][0] = LDB3(b3, nt, 0); bf[nt][1] = LDB3(b3, nt, 1); } \
    if (t + 2 < 32) { \
      STGB2M(b3n2, t + 2); \
      asm volatile("s_waitcnt vmcnt(2)" ::: "memory"); \
    } else { \
      asm volatile("s_waitcnt vmcnt(0)" ::: "memory"); \
    } \
    __builtin_amdgcn_s_barrier(); \
    asm volatile("s_waitcnt lgkmcnt(0)" ::: "memory"); \
    __builtin_amdgcn_sched_barrier(0); \
    MFMA_P(2); \
    __builtin_amdgcn_s_barrier(); \
    b3 = (b3 == 2) ? 0 : b3 + 1; \
    b3n2 = (b3n2 == 2) ? 0 : b3n2 + 1; \
  }

// ---------------- Fused QKV GEMM: 256x128 tiles, 768 blocks = 3/CU exactly ------
// RoPE fused in epilogue; Q scaled by log2(e)/sqrt(DH) (exp2-domain softmax).
__global__ __launch_bounds__(512, 2)
void gemm_qkv(const short* __restrict__ A,
              const short* __restrict__ Wq, const short* __restrict__ Wk,
              const short* __restrict__ Wv, const int* __restrict__ pos,
              short* __restrict__ Qo, short* __restrict__ Ko, short* __restrict__ Vo) {
  __shared__ __align__(16) short sm[57344];   // 112 KiB: A[2][256][64] | B[3][128][64]
  const int tid = threadIdx.x;
  const int lane = tid & 63;
  const int wave = tid >> 6;                  // 0..7
  const int quad = lane >> 4, l16 = lane & 15;
  const int wm = wave >> 1, wn = wave & 1;    // wave tile: 64 rows x 64 cols

  // bijective XCD swizzle (768 % 8 == 0): XCD j owns logical tiles [j*96, j*96+96)
  const int wid = (blockIdx.x & 7) * 96 + (blockIdx.x >> 3);
  const int wsel = wid >> 8;                  // 0=Q 1=K 2=V (wsel-major: per-round
  const int idr = wid & 255;                  //  working set = A + one weight matrix)
  const int bm = (idr >> 4) * 256;
  const int bn = (idr & 15) * 128;
  const short* Bw = (wsel == 0) ? Wq : (wsel == 1) ? Wk : Wv;
  short* Cout = (wsel == 0) ? Qo : (wsel == 1) ? Ko : Vo;

  short* smA = sm;                 // bufs at +0, +16384 shorts
  short* smB = sm + 32768;         // bufs at +0, +8192, +16384 shorts
  const int wst = wave * 512;      // wave's staging base within a 64-row group

  const int srow = tid >> 3;                          // 0..63
  const int scol = ((tid & 7) ^ (srow & 7)) * 8;      // pre-swizzled col (shorts)
  const short* aBase = A  + (size_t)(bm + srow) * DD + scol;
  const short* bBase = Bw + (size_t)(bn + srow) * DD + scol;

  f32x4 acc[4][4] = {};
  bf16x8 af[4][2], bf[4][2];

  GEMM_KLOOP

  // ---- RoPE in-register for Q/K (pairs = adjacent lanes via DPP xor1) ----
  if (wsel < 2) {
    const float post = (wsel == 0) ? 0.1275174306f : 1.0f;  // log2(e)/sqrt(128)
    float fr[4];
    #pragma unroll
    for (int nt = 0; nt < 4; ++nt) {
      int pi = wn * 32 + nt * 8 + (l16 >> 1);              // pair index 0..63
      fr[nt] = __expf(-0.14391156831f * (float)pi);        // theta^(-pi/64)
    }
    const float sgn = (l16 & 1) ? 1.0f : -1.0f;
    #pragma unroll
    for (int mt = 0; mt < 4; ++mt) {
      #pragma unroll
      for (int r = 0; r < 4; ++r) {
        int m = bm + wm*64 + mt*16 + quad*4 + r;
        float fp = (float)pos[m & 2047];
        #pragma unroll
        for (int nt = 0; nt < 4; ++nt) {
          float v = acc[mt][nt][r];
          float p = dppf<0xB1>(v);               // partner (d^1) value
          float ang = fp * fr[nt];
          float sn = __sinf(ang), cs = __cosf(ang);
          acc[mt][nt][r] = (v * cs + sgn * p * sn) * post;
        }
      }
    }
  }

  #pragma unroll
  for (int mt = 0; mt < 4; ++mt)
    #pragma unroll
    for (int nt = 0; nt < 4; ++nt)
      #pragma unroll
      for (int r = 0; r < 4; ++r) {
        int m = bm + wm*64 + mt*16 + quad*4 + r;
        int n = bn + wn*64 + nt*16 + l16;
        int b = m >> 11, s = m & 2047;
        int h = n >> 7,  d = n & 127;
        Cout[(((size_t)(b*HH + h)*SS + s)*DHH) + d] = f2b(acc[mt][nt][r]);
      }
}

// ---------------- O-projection GEMM: same template, 256 blocks = 1/CU -----------
__global__ __launch_bounds__(512, 2)
void gemm_o(const short* __restrict__ A, const short* __restrict__ Bw,
            float* __restrict__ Cout) {
  __shared__ __align__(16) short sm[57344];   // 112 KiB
  const int tid = threadIdx.x;
  const int lane = tid & 63;
  const int wave = tid >> 6;
  const int quad = lane >> 4, l16 = lane & 15;
  const int wm = wave >> 1, wn = wave & 1;

  const int wid = (blockIdx.x & 7) * 32 + (blockIdx.x >> 3);  // 256 % 8 == 0
  const int bm = (wid >> 4) * 256;
  const int bn = (wid & 15) * 128;

  short* smA = sm;
  short* smB = sm + 32768;
  const int wst = wave * 512;

  const int srow = tid >> 3;
  const int scol = ((tid & 7) ^ (srow & 7)) * 8;
  const short* aBase = A  + (size_t)(bm + srow) * DD + scol;
  const short* bBase = Bw + (size_t)(bn + srow) * DD + scol;

  f32x4 acc[4][4] = {};
  bf16x8 af[4][2], bf[4][2];

  GEMM_KLOOP

  #pragma unroll
  for (int mt = 0; mt < 4; ++mt)
    #pragma unroll
    for (int nt = 0; nt < 4; ++nt)
      #pragma unroll
      for (int r = 0; r < 4; ++r) {
        int m = bm + wm*64 + mt*16 + quad*4 + r;
        int n = bn + wn*64 + nt*16 + l16;
        Cout[(size_t)m * DD + n] = acc[mt][nt][r];
      }
}

// ---------------- Flash attention (causal), one 64-row Q tile per block ----------
// 256 threads (4 waves); all waves active every iteration. Balanced grid:
// co-resident quads {s,s+8,s+16,s+24} sum to 66 k-tile units, same bh.
// Spill-free design: K staged via global_load_lds (pre-swizzled source, no kreg);
// V reg-prefetch (16 VGPR) with counted vmcnt(4) kept in flight across barrier;
// plain online softmax (exp2 domain). launch_bounds(256,3): no forced spill.
__global__ __launch_bounds__(256, 3)
void attn(const short* __restrict__ Q, const short* __restrict__ K,
          const short* __restrict__ V, short* __restrict__ O) {
  __shared__ __align__(16) short Ks[64*128];    // 16 KB [key][dim], swizzled
  __shared__ __align__(16) short Vt[128*64];    // 16 KB [dim][key], swizzled
  __shared__ __align__(16) short Pb[4*16*64];   // 8 KB per-wave P, swizzled
  const int tid = threadIdx.x;
  const int lane = tid & 63, wave = tid >> 6;   // wave 0..3
  const int quad = lane >> 4, l16 = lane & 15;
  const int L = blockIdx.x;
  const int bh = L & 31;
  const int s = L >> 5;                         // 0..31
  const int qt = (s < 8) ? 31 - s : (s < 16) ? s - 8 : (s < 24) ? 39 - s : s - 16;
  const int b = bh >> 4, h = bh & 15;
  const short* Kg = K + (size_t)bh * SS * DHH;
  const short* Vg = V + (size_t)bh * SS * DHH;
  const int qbase = qt * 64 + wave * 16;

  bf16x8 aq[4];
  {
    const short* qp = Q + ((size_t)bh * SS + qbase + l16) * DHH + quad*8;
    #pragma unroll
    for (int ks = 0; ks < 4; ++ks) aq[ks] = *(const bf16x8*)(qp + ks*32);
  }

  f32x4 o[8] = {};
  float mrow[4], lrow[4];
  #pragma unroll
  for (int r = 0; r < 4; ++r) { mrow[r] = -1e30f; lrow[r] = 0.f; }

  // K staging geometry: LDS linear (wave,j,lane) -> key = wave*16+j*4+(lane>>4),
  // colb = (lane&15)*16; global source col pre-swizzled (both-sides rule).
  const int skey0 = wave*16 + (lane >> 4);
  const int scolb = (lane & 15) << 4;
  // V staging geometry (reg transpose)
  const int vkp = (tid & 31) * 2;
  const int vds = (tid >> 5) * 16;

  const int nkt = qt + 1;
  int4 vreg[4];
  {
    const short* vp = Vg + (size_t)vkp * DHH + vds;
    vreg[0] = *(const int4*)vp;         vreg[1] = *(const int4*)(vp + 8);
    vreg[2] = *(const int4*)(vp + DHH); vreg[3] = *(const int4*)(vp + DHH + 8);
  }

  for (int kt = 0; kt < nkt; ++kt) {
    // ---- stage K(kt) direct to LDS (async, 4 x 1KB/wave) ----
    {
      const short* Kt = Kg + (size_t)kt * 64 * DHH;
      #pragma unroll
      for (int j = 0; j < 4; ++j) {
        int key = skey0 + j*4;
        GLOAD_LDS16(Kt + (size_t)key * DHH + ((scolb ^ ((key & 7) << 4)) >> 1),
                    Ks + wave*2048 + j*512);
      }
    }
    asm volatile("" ::: "memory");   // pin: V loads must issue AFTER K gloads
    // ---- V(kt): transpose-write from regs, swizzled ----
    {
      const short* s0 = (const short*)&vreg[0];   // key vkp,   dims vds..+15
      const short* s1 = (const short*)&vreg[2];   // key vkp+1, dims vds..+15
      #pragma unroll
      for (int e = 0; e < 16; ++e) {
        int dim = vds + e;
        int val = (int)(unsigned short)s0[e] | ((int)(unsigned short)s1[e] << 16);
        *(int*)((char*)Vt + dim*128 + ((vkp*2) ^ ((dim & 7) << 4))) = val;
      }
    }
    // ---- prefetch V(kt+1) into regs; counted wait keeps it in flight ----
    if (kt + 1 < nkt) {
      const short* vp = Vg + (size_t)((kt+1)*64 + vkp) * DHH + vds;
      vreg[0] = *(const int4*)vp;         vreg[1] = *(const int4*)(vp + 8);
      vreg[2] = *(const int4*)(vp + DHH); vreg[3] = *(const int4*)(vp + DHH + 8);
      asm volatile("s_waitcnt vmcnt(4) lgkmcnt(0)" ::: "memory");  // K done, V in flight
    } else {
      asm volatile("s_waitcnt vmcnt(0) lgkmcnt(0)" ::: "memory");
    }
    __builtin_amdgcn_s_barrier();
    __builtin_amdgcn_sched_barrier(0);

    // ---- QK^T: 16 queries x 64 keys ----
    float sv[4][4];
    __builtin_amdgcn_s_setprio(1);
    #pragma unroll
    for (int nt = 0; nt < 4; ++nt) {
      f32x4 a = {0.f, 0.f, 0.f, 0.f};
      #pragma unroll
      for (int ks = 0; ks < 4; ++ks) {
        int key = nt*16 + l16;
        bf16x8 bk = *(const bf16x8*)((const char*)Ks + key*256 +
                       ((ks*64 + quad*16) ^ ((key & 7) << 4)));
        a = __builtin_amdgcn_mfma_f32_16x16x32_bf16(aq[ks], bk, a, 0, 0, 0);
      }
      #pragma unroll
      for (int r = 0; r < 4; ++r) sv[nt][r] = a[r];
    }
    __builtin_amdgcn_s_setprio(0);

    // ---- causal mask on the diagonal tile ----
    if (kt == qt) {
      #pragma unroll
      for (int nt = 0; nt < 4; ++nt)
        #pragma unroll
        for (int r = 0; r < 4; ++r)
          if (nt*16 + l16 > wave*16 + quad*4 + r) sv[nt][r] = -1e30f;
    }

    // ---- online softmax (exp2 domain, plain rescale) ----
    #pragma unroll
    for (int r = 0; r < 4; ++r) {
      float mx = fmaxf(fmaxf(sv[0][r], sv[1][r]), fmaxf(sv[2][r], sv[3][r]));
      mx = rmax16(mx);
      float mnew = fmaxf(mrow[r], mx);
      float alpha = EXP2F(mrow[r] - mnew);
      float ls = 0.f;
      #pragma unroll
      for (int nt = 0; nt < 4; ++nt) {
        float pv = EXP2F(sv[nt][r] - mnew);
        sv[nt][r] = pv; ls += pv;
      }
      ls = rsum16(ls);
      lrow[r] = lrow[r] * alpha + ls;
      mrow[r] = mnew;
      #pragma unroll
      for (int nt = 0; nt < 8; ++nt) o[nt][r] *= alpha;
    }

    // ---- P -> LDS (per-wave region, swizzled) ----
    #pragma unroll
    for (int nt = 0; nt < 4; ++nt)
      #pragma unroll
      for (int r = 0; r < 4; ++r) {
        int qr = quad*4 + r;
        *(short*)((char*)Pb + wave*2048 + qr*128 +
                  (((nt*16 + l16)*2) ^ ((qr & 7) << 4))) = f2b_fast(sv[nt][r]);
      }

    bf16x8 ap[2];
    #pragma unroll
    for (int k2 = 0; k2 < 2; ++k2)
      ap[k2] = *(const bf16x8*)((const char*)Pb + wave*2048 + l16*128 +
                  ((k2*64 + quad*16) ^ ((l16 & 7) << 4)));

    // ---- PV ----
    __builtin_amdgcn_s_setprio(1);
    #pragma unroll
    for (int k2 = 0; k2 < 2; ++k2)
      #pragma unroll
      for (int nt = 0; nt < 8; ++nt) {
        int d = nt*16 + l16;
        bf16x8 bv = *(const bf16x8*)((const char*)Vt + d*128 +
                       ((k2*64 + quad*16) ^ ((d & 7) << 4)));
        o[nt] = __builtin_amdgcn_mfma_f32_16x16x32_bf16(ap[k2], bv, o[nt], 0, 0, 0);
      }
    __builtin_amdgcn_s_setprio(0);

    // ---- end of iter: LDS reads drained; V prefetch stays in flight ----
    asm volatile("s_waitcnt lgkmcnt(0)" ::: "memory");
    __builtin_amdgcn_s_barrier();
    __builtin_amdgcn_sched_barrier(0);
  }

  #pragma unroll
  for (int nt = 0; nt < 8; ++nt)
    #pragma unroll
    for (int r = 0; r < 4; ++r) {
      int q = qbase + quad*4 + r;
      float v = o[nt][r] / lrow[r];
      O[((size_t)(b*SS + q)) * DD + h*DHH + nt*16 + l16] = f2b(v);
    }
}

extern "C" void kernel_launch(void* const* d_in, const int* in_sizes, int n_in,
                              void* d_out, int out_size, void* d_ws, size_t ws_size,
                              hipStream_t stream) {
  const float* x  = (const float*)d_in[0];
  const int* pos  = (const int*)d_in[1];
  const float* Wq = (const float*)d_in[2];
  const float* Wk = (const float*)d_in[3];
  const float* Wv = (const float*)d_in[4];
  const float* Wo = (const float*)d_in[5];

  char* ws = (char*)d_ws;
  short* xb  = (short*)(ws);
  short* wqb = (short*)(ws + 16777216);
  short* wkb = (short*)(ws + 25165824);
  short* wvb = (short*)(ws + 33554432);
  short* wob = (short*)(ws + 41943040);
  short* Qb  = (short*)(ws + 50331648);
  short* Kb  = (short*)(ws + 67108864);
  short* Vb  = (short*)(ws + 83886080);
  short* Ob  = (short*)(ws + 100663296);

  cvt_all<<<24576, 256, 0, stream>>>(x, Wq, Wk, Wv, Wo, xb, wqb, wkb, wvb, wob);

  // fused QKV: 768 blocks (3 mats x 16 M x 16 N) = exactly 3 blocks/CU
  gemm_qkv<<<768, 512, 0, stream>>>(xb, wqb, wkb, wvb, pos, Qb, Kb, Vb);

  attn<<<1024, 256, 0, stream>>>(Qb, Kb, Vb, Ob);   // balanced quads, 40 KB LDS

  // O-projection: 256 blocks (16 M x 16 N) = exactly 1 block/CU
  gemm_o<<<256, 512, 0, stream>>>(Ob, wob, (float*)d_out);
}

// Round 6
// 379.743 us; speedup vs baseline: 2.5633x; 1.0020x over previous
//
#include <hip/hip_runtime.h>
#include <hip/hip_bf16.h>
#include <math.h>

#define BB 2
#define SS 2048
#define DD 2048
#define HH 16
#define DHH 128
#define MM (BB*SS)   // 4096

typedef __attribute__((ext_vector_type(8))) short bf16x8;
typedef __attribute__((ext_vector_type(4))) float f32x4;

#define AS1 __attribute__((address_space(1)))
#define AS3 __attribute__((address_space(3)))
#define GLOAD_LDS16(g, l) __builtin_amdgcn_global_load_lds((const AS1 void*)(g), (AS3 void*)(l), 16, 0, 0)

#if __has_builtin(__builtin_amdgcn_exp2f)
#define EXP2F(x) __builtin_amdgcn_exp2f(x)
#else
#define EXP2F(x) exp2f(x)
#endif

__device__ __forceinline__ float b2f(short s) {
  union { unsigned int u; float f; } v;
  v.u = ((unsigned int)(unsigned short)s) << 16;
  return v.f;
}
__device__ __forceinline__ short f2b(float f) {
  union { float f; unsigned int u; } v; v.f = f;
  unsigned int u = v.u;
  u += 0x7fffu + ((u >> 16) & 1u);   // round-to-nearest-even
  return (short)(u >> 16);
}
// fast round-half-up; valid for non-negative finite values
__device__ __forceinline__ short f2b_fast(float f) {
  union { float f; unsigned int u; } v; v.f = f;
  return (short)((v.u + 0x8000u) >> 16);
}

// ---- DPP helpers (VALU pipe, no LDS ops) ----
template<int CTRL>
__device__ __forceinline__ float dppf(float x) {
  int xi = __builtin_bit_cast(int, x);
  int r = __builtin_amdgcn_update_dpp(0, xi, CTRL, 0xf, 0xf, true);
  return __builtin_bit_cast(float, r);
}
__device__ __forceinline__ float rmax16(float x) {
  x = fmaxf(x, dppf<0xB1>(x));   // quad_perm xor1
  x = fmaxf(x, dppf<0x4E>(x));   // quad_perm xor2
  x = fmaxf(x, dppf<0x141>(x));  // row_half_mirror
  x = fmaxf(x, dppf<0x140>(x));  // row_mirror
  return x;
}
__device__ __forceinline__ float rsum16(float x) {
  x += dppf<0xB1>(x);
  x += dppf<0x4E>(x);
  x += dppf<0x141>(x);
  x += dppf<0x140>(x);
  return x;
}

// ---------------- fp32 -> bf16 convert, all 5 tensors in one launch ----------------
__global__ void cvt_all(const float* __restrict__ x,  const float* __restrict__ wq,
                        const float* __restrict__ wk, const float* __restrict__ wv,
                        const float* __restrict__ wo,
                        short* __restrict__ xb,  short* __restrict__ wqb,
                        short* __restrict__ wkb, short* __restrict__ wvb,
                        short* __restrict__ wob) {
  int i = blockIdx.x * blockDim.x + threadIdx.x;   // float4 index
  const float* src; short* dst; int off;
  if (i < 2097152) { src = x; dst = xb; off = i; }
  else {
    int j = i - 2097152;
    int w = j >> 20; off = j & 1048575;
    src = (w == 0) ? wq : (w == 1) ? wk : (w == 2) ? wv : wo;
    dst = (w == 0) ? wqb : (w == 1) ? wkb : (w == 2) ? wvb : wob;
  }
  float4 v = ((const float4*)src)[i < 2097152 ? off : off];
  short4 o;
  o.x = f2b(v.x); o.y = f2b(v.y); o.z = f2b(v.z); o.w = f2b(v.w);
  ((short4*)dst)[off] = o;
}

// =============== 256x128-tile 8-wave GEMM template (2-phase, deep prefetch) ======
// 8 waves as 4M x 2N (wave tile 64x64), BK=64. LDS: A tribuf 96K + B tribuf 48K
// = 144 KiB (1 block/CU). T2 swizzle via pre-swizzled global source
// (global_load_lds writes linearly). BOTH A and B staged 2 tiles ahead;
// counted vmcnt(6) == m201's depth (6 loads in flight, never drains mid-loop).
// Queue at t.P2 wait: [A(t+1):4, B(t+1):2, A(t+2):4, B(t+2):2] -> vmcnt(6)
// retires exactly tile t+1; issue->wait distance = 6 phases >> HBM latency.
// WAR safe: stage target (t+2)%3 == (t-1)%3, readers drained 2+ barriers ago.
#define LDA3(b, mt, kk) (*(const bf16x8*)((const char*)smA + (b)*32768 + \
    (wm*64 + (mt)*16 + l16)*128 + ((((kk)*64) + quad*16) ^ ((l16 & 7) << 4))))
#define LDB3(b, nt, kk) (*(const bf16x8*)((const char*)smB + (b)*16384 + \
    (wn*64 + (nt)*16 + l16)*128 + ((((kk)*64) + quad*16) ^ ((l16 & 7) << 4))))
#define STGA4(b, t) do { \
    _Pragma("unroll") \
    for (int h = 0; h < 4; ++h) \
      GLOAD_LDS16(aBase + (size_t)(h*64) * DD + (t)*64, smA + (b)*16384 + h*4096 + wst); } while(0)
#define STGB2M(b, t) do { \
    _Pragma("unroll") \
    for (int h = 0; h < 2; ++h) \
      GLOAD_LDS16(bBase + (size_t)(h*64) * DD + (t)*64, smB + (b)*8192 + h*4096 + wst); } while(0)
#define MFMA_P(NT0) do { \
    __builtin_amdgcn_s_setprio(1); \
    _Pragma("unroll") \
    for (int mt = 0; mt < 4; ++mt) \
      _Pragma("unroll") \
      for (int nt = 0; nt < 2; ++nt) \
        _Pragma("unroll") \
        for (int kk = 0; kk < 2; ++kk) \
          acc[mt][(NT0) + nt] = __builtin_amdgcn_mfma_f32_16x16x32_bf16( \
              af[mt][kk], bf[(NT0) + nt][kk], acc[mt][(NT0) + nt], 0, 0, 0); \
    __builtin_amdgcn_s_setprio(0); } while(0)

#define GEMM_KLOOP \
  STGA4(0, 0); STGB2M(0, 0); \
  STGA4(1, 1); STGB2M(1, 1); \
  asm volatile("s_waitcnt vmcnt(6)" ::: "memory"); \
  __builtin_amdgcn_s_barrier(); \
  int bc = 0, bs = 2; \
  for (int t = 0; t < 32; ++t) { \
    _Pragma("unroll") \
    for (int mt = 0; mt < 4; ++mt) { af[mt][0] = LDA3(bc, mt, 0); af[mt][1] = LDA3(bc, mt, 1); } \
    _Pragma("unroll") \
    for (int nt = 0; nt < 2; ++nt) { bf[nt][0] = LDB3(bc, nt, 0); bf[nt][1] = LDB3(bc, nt, 1); } \
    if (t + 2 < 32) STGA4(bs, t + 2); \
    __builtin_amdgcn_s_barrier(); \
    asm volatile("s_waitcnt lgkmcnt(0)" ::: "memory"); \
    __builtin_amdgcn_sched_barrier(0); \
    MFMA_P(0); \
    __builtin_amdgcn_s_barrier(); \
    _Pragma("unroll") \
    for (int nt = 2; nt < 4; ++nt) { bf[nt][0] = LDB3(bc, nt, 0); bf[nt][1] = LDB3(bc, nt, 1); } \
    if (t + 2 < 32) { \
      STGB2M(bs, t + 2); \
      asm volatile("s_waitcnt vmcnt(6)" ::: "memory"); \
    } else { \
      asm volatile("s_waitcnt vmcnt(0)" ::: "memory"); \
    } \
    __builtin_amdgcn_s_barrier(); \
    asm volatile("s_waitcnt lgkmcnt(0)" ::: "memory"); \
    __builtin_amdgcn_sched_barrier(0); \
    MFMA_P(2); \
    __builtin_amdgcn_s_barrier(); \
    bc = (bc == 2) ? 0 : bc + 1; \
    bs = (bs == 2) ? 0 : bs + 1; \
  }

// ---------------- Fused QKV GEMM: 256x128 tiles, 768 blocks (3 clean rounds) ----
// RoPE fused in epilogue; Q scaled by log2(e)/sqrt(DH) (exp2-domain softmax).
__global__ __launch_bounds__(512, 1)
void gemm_qkv(const short* __restrict__ A,
              const short* __restrict__ Wq, const short* __restrict__ Wk,
              const short* __restrict__ Wv, const int* __restrict__ pos,
              short* __restrict__ Qo, short* __restrict__ Ko, short* __restrict__ Vo) {
  __shared__ __align__(16) short sm[73728];   // 144 KiB: A[3][256][64] | B[3][128][64]
  const int tid = threadIdx.x;
  const int lane = tid & 63;
  const int wave = tid >> 6;                  // 0..7
  const int quad = lane >> 4, l16 = lane & 15;
  const int wm = wave >> 1, wn = wave & 1;    // wave tile: 64 rows x 64 cols

  // bijective XCD swizzle (768 % 8 == 0): XCD j owns logical tiles [j*96, j*96+96)
  const int wid = (blockIdx.x & 7) * 96 + (blockIdx.x >> 3);
  const int wsel = wid >> 8;                  // 0=Q 1=K 2=V (wsel-major: per-round
  const int idr = wid & 255;                  //  working set = A + one weight matrix)
  const int bm = (idr >> 4) * 256;
  const int bn = (idr & 15) * 128;
  const short* Bw = (wsel == 0) ? Wq : (wsel == 1) ? Wk : Wv;
  short* Cout = (wsel == 0) ? Qo : (wsel == 1) ? Ko : Vo;

  short* smA = sm;                 // bufs at +0, +16384, +32768 shorts
  short* smB = sm + 49152;         // bufs at +0, +8192, +16384 shorts
  const int wst = wave * 512;      // wave's staging base within a 64-row group

  const int srow = tid >> 3;                          // 0..63
  const int scol = ((tid & 7) ^ (srow & 7)) * 8;      // pre-swizzled col (shorts)
  const short* aBase = A  + (size_t)(bm + srow) * DD + scol;
  const short* bBase = Bw + (size_t)(bn + srow) * DD + scol;

  f32x4 acc[4][4] = {};
  bf16x8 af[4][2], bf[4][2];

  GEMM_KLOOP

  // ---- RoPE in-register for Q/K (pairs = adjacent lanes via DPP xor1) ----
  if (wsel < 2) {
    const float post = (wsel == 0) ? 0.1275174306f : 1.0f;  // log2(e)/sqrt(128)
    float fr[4];
    #pragma unroll
    for (int nt = 0; nt < 4; ++nt) {
      int pi = wn * 32 + nt * 8 + (l16 >> 1);              // pair index 0..63
      fr[nt] = __expf(-0.14391156831f * (float)pi);        // theta^(-pi/64)
    }
    const float sgn = (l16 & 1) ? 1.0f : -1.0f;
    #pragma unroll
    for (int mt = 0; mt < 4; ++mt) {
      #pragma unroll
      for (int r = 0; r < 4; ++r) {
        int m = bm + wm*64 + mt*16 + quad*4 + r;
        float fp = (float)pos[m & 2047];
        #pragma unroll
        for (int nt = 0; nt < 4; ++nt) {
          float v = acc[mt][nt][r];
          float p = dppf<0xB1>(v);               // partner (d^1) value
          float ang = fp * fr[nt];
          float sn = __sinf(ang), cs = __cosf(ang);
          acc[mt][nt][r] = (v * cs + sgn * p * sn) * post;
        }
      }
    }
  }

  #pragma unroll
  for (int mt = 0; mt < 4; ++mt)
    #pragma unroll
    for (int nt = 0; nt < 4; ++nt)
      #pragma unroll
      for (int r = 0; r < 4; ++r) {
        int m = bm + wm*64 + mt*16 + quad*4 + r;
        int n = bn + wn*64 + nt*16 + l16;
        int b = m >> 11, s = m & 2047;
        int h = n >> 7,  d = n & 127;
        Cout[(((size_t)(b*HH + h)*SS + s)*DHH) + d] = f2b(acc[mt][nt][r]);
      }
}

// ---------------- O-projection GEMM: same template, 256 blocks = 1/CU -----------
__global__ __launch_bounds__(512, 1)
void gemm_o(const short* __restrict__ A, const short* __restrict__ Bw,
            float* __restrict__ Cout) {
  __shared__ __align__(16) short sm[73728];   // 144 KiB
  const int tid = threadIdx.x;
  const int lane = tid & 63;
  const int wave = tid >> 6;
  const int quad = lane >> 4, l16 = lane & 15;
  const int wm = wave >> 1, wn = wave & 1;

  const int wid = (blockIdx.x & 7) * 32 + (blockIdx.x >> 3);  // 256 % 8 == 0
  const int bm = (wid >> 4) * 256;
  const int bn = (wid & 15) * 128;

  short* smA = sm;
  short* smB = sm + 49152;
  const int wst = wave * 512;

  const int srow = tid >> 3;
  const int scol = ((tid & 7) ^ (srow & 7)) * 8;
  const short* aBase = A  + (size_t)(bm + srow) * DD + scol;
  const short* bBase = Bw + (size_t)(bn + srow) * DD + scol;

  f32x4 acc[4][4] = {};
  bf16x8 af[4][2], bf[4][2];

  GEMM_KLOOP

  #pragma unroll
  for (int mt = 0; mt < 4; ++mt)
    #pragma unroll
    for (int nt = 0; nt < 4; ++nt)
      #pragma unroll
      for (int r = 0; r < 4; ++r) {
        int m = bm + wm*64 + mt*16 + quad*4 + r;
        int n = bn + wn*64 + nt*16 + l16;
        Cout[(size_t)m * DD + n] = acc[mt][nt][r];
      }
}

// ---------------- Flash attention (causal), one 64-row Q tile per block ----------
// 256 threads (4 waves); all waves active every iteration. Balanced grid:
// co-resident quads {s,s+8,s+16,s+24} sum to 66 k-tile units, same bh.
// Spill-free design: K staged via global_load_lds (pre-swizzled source, no kreg);
// V reg-prefetch (16 VGPR) with counted vmcnt(4) kept in flight across barrier;
// plain online softmax (exp2 domain). launch_bounds(256,3): no forced spill.
__global__ __launch_bounds__(256, 3)
void attn(const short* __restrict__ Q, const short* __restrict__ K,
          const short* __restrict__ V, short* __restrict__ O) {
  __shared__ __align__(16) short Ks[64*128];    // 16 KB [key][dim], swizzled
  __shared__ __align__(16) short Vt[128*64];    // 16 KB [dim][key], swizzled
  __shared__ __align__(16) short Pb[4*16*64];   // 8 KB per-wave P, swizzled
  const int tid = threadIdx.x;
  const int lane = tid & 63, wave = tid >> 6;   // wave 0..3
  const int quad = lane >> 4, l16 = lane & 15;
  const int L = blockIdx.x;
  const int bh = L & 31;
  const int s = L >> 5;                         // 0..31
  const int qt = (s < 8) ? 31 - s : (s < 16) ? s - 8 : (s < 24) ? 39 - s : s - 16;
  const int b = bh >> 4, h = bh & 15;
  const short* Kg = K + (size_t)bh * SS * DHH;
  const short* Vg = V + (size_t)bh * SS * DHH;
  const int qbase = qt * 64 + wave * 16;

  bf16x8 aq[4];
  {
    const short* qp = Q + ((size_t)bh * SS + qbase + l16) * DHH + quad*8;
    #pragma unroll
    for (int ks = 0; ks < 4; ++ks) aq[ks] = *(const bf16x8*)(qp + ks*32);
  }

  f32x4 o[8] = {};
  float mrow[4], lrow[4];
  #pragma unroll
  for (int r = 0; r < 4; ++r) { mrow[r] = -1e30f; lrow[r] = 0.f; }

  // K staging geometry: LDS linear (wave,j,lane) -> key = wave*16+j*4+(lane>>4),
  // colb = (lane&15)*16; global source col pre-swizzled (both-sides rule).
  const int skey0 = wave*16 + (lane >> 4);
  const int scolb = (lane & 15) << 4;
  // V staging geometry (reg transpose)
  const int vkp = (tid & 31) * 2;
  const int vds = (tid >> 5) * 16;

  const int nkt = qt + 1;
  int4 vreg[4];
  {
    const short* vp = Vg + (size_t)vkp * DHH + vds;
    vreg[0] = *(const int4*)vp;         vreg[1] = *(const int4*)(vp + 8);
    vreg[2] = *(const int4*)(vp + DHH); vreg[3] = *(const int4*)(vp + DHH + 8);
  }

  for (int kt = 0; kt < nkt; ++kt) {
    // ---- stage K(kt) direct to LDS (async, 4 x 1KB/wave) ----
    {
      const short* Kt = Kg + (size_t)kt * 64 * DHH;
      #pragma unroll
      for (int j = 0; j < 4; ++j) {
        int key = skey0 + j*4;
        GLOAD_LDS16(Kt + (size_t)key * DHH + ((scolb ^ ((key & 7) << 4)) >> 1),
                    Ks + wave*2048 + j*512);
      }
    }
    asm volatile("" ::: "memory");   // pin: V loads must issue AFTER K gloads
    // ---- V(kt): transpose-write from regs, swizzled ----
    {
      const short* s0 = (const short*)&vreg[0];   // key vkp,   dims vds..+15
      const short* s1 = (const short*)&vreg[2];   // key vkp+1, dims vds..+15
      #pragma unroll
      for (int e = 0; e < 16; ++e) {
        int dim = vds + e;
        int val = (int)(unsigned short)s0[e] | ((int)(unsigned short)s1[e] << 16);
        *(int*)((char*)Vt + dim*128 + ((vkp*2) ^ ((dim & 7) << 4))) = val;
      }
    }
    // ---- prefetch V(kt+1) into regs; counted wait keeps it in flight ----
    if (kt + 1 < nkt) {
      const short* vp = Vg + (size_t)((kt+1)*64 + vkp) * DHH + vds;
      vreg[0] = *(const int4*)vp;         vreg[1] = *(const int4*)(vp + 8);
      vreg[2] = *(const int4*)(vp + DHH); vreg[3] = *(const int4*)(vp + DHH + 8);
      asm volatile("s_waitcnt vmcnt(4) lgkmcnt(0)" ::: "memory");  // K done, V in flight
    } else {
      asm volatile("s_waitcnt vmcnt(0) lgkmcnt(0)" ::: "memory");
    }
    __builtin_amdgcn_s_barrier();
    __builtin_amdgcn_sched_barrier(0);

    // ---- QK^T: 16 queries x 64 keys ----
    float sv[4][4];
    __builtin_amdgcn_s_setprio(1);
    #pragma unroll
    for (int nt = 0; nt < 4; ++nt) {
      f32x4 a = {0.f, 0.f, 0.f, 0.f};
      #pragma unroll
      for (int ks = 0; ks < 4; ++ks) {
        int key = nt*16 + l16;
        bf16x8 bk = *(const bf16x8*)((const char*)Ks + key*256 +
                       ((ks*64 + quad*16) ^ ((key & 7) << 4)));
        a = __builtin_amdgcn_mfma_f32_16x16x32_bf16(aq[ks], bk, a, 0, 0, 0);
      }
      #pragma unroll
      for (int r = 0; r < 4; ++r) sv[nt][r] = a[r];
    }
    __builtin_amdgcn_s_setprio(0);

    // ---- causal mask on the diagonal tile ----
    if (kt == qt) {
      #pragma unroll
      for (int nt = 0; nt < 4; ++nt)
        #pragma unroll
        for (int r = 0; r < 4; ++r)
          if (nt*16 + l16 > wave*16 + quad*4 + r) sv[nt][r] = -1e30f;
    }

    // ---- online softmax (exp2 domain, plain rescale) ----
    #pragma unroll
    for (int r = 0; r < 4; ++r) {
      float mx = fmaxf(fmaxf(sv[0][r], sv[1][r]), fmaxf(sv[2][r], sv[3][r]));
      mx = rmax16(mx);
      float mnew = fmaxf(mrow[r], mx);
      float alpha = EXP2F(mrow[r] - mnew);
      float ls = 0.f;
      #pragma unroll
      for (int nt = 0; nt < 4; ++nt) {
        float pv = EXP2F(sv[nt][r] - mnew);
        sv[nt][r] = pv; ls += pv;
      }
      ls = rsum16(ls);
      lrow[r] = lrow[r] * alpha + ls;
      mrow[r] = mnew;
      #pragma unroll
      for (int nt = 0; nt < 8; ++nt) o[nt][r] *= alpha;
    }

    // ---- P -> LDS (per-wave region, swizzled) ----
    #pragma unroll
    for (int nt = 0; nt < 4; ++nt)
      #pragma unroll
      for (int r = 0; r < 4; ++r) {
        int qr = quad*4 + r;
        *(short*)((char*)Pb + wave*2048 + qr*128 +
                  (((nt*16 + l16)*2) ^ ((qr & 7) << 4))) = f2b_fast(sv[nt][r]);
      }

    bf16x8 ap[2];
    #pragma unroll
    for (int k2 = 0; k2 < 2; ++k2)
      ap[k2] = *(const bf16x8*)((const char*)Pb + wave*2048 + l16*128 +
                  ((k2*64 + quad*16) ^ ((l16 & 7) << 4)));

    // ---- PV ----
    __builtin_amdgcn_s_setprio(1);
    #pragma unroll
    for (int k2 = 0; k2 < 2; ++k2)
      #pragma unroll
      for (int nt = 0; nt < 8; ++nt) {
        int d = nt*16 + l16;
        bf16x8 bv = *(const bf16x8*)((const char*)Vt + d*128 +
                       ((k2*64 + quad*16) ^ ((d & 7) << 4)));
        o[nt] = __builtin_amdgcn_mfma_f32_16x16x32_bf16(ap[k2], bv, o[nt], 0, 0, 0);
      }
    __builtin_amdgcn_s_setprio(0);

    // ---- end of iter: LDS reads drained; V prefetch stays in flight ----
    asm volatile("s_waitcnt lgkmcnt(0)" ::: "memory");
    __builtin_amdgcn_s_barrier();
    __builtin_amdgcn_sched_barrier(0);
  }

  #pragma unroll
  for (int nt = 0; nt < 8; ++nt)
    #pragma unroll
    for (int r = 0; r < 4; ++r) {
      int q = qbase + quad*4 + r;
      float v = o[nt][r] / lrow[r];
      O[((size_t)(b*SS + q)) * DD + h*DHH + nt*16 + l16] = f2b(v);
    }
}

extern "C" void kernel_launch(void* const* d_in, const int* in_sizes, int n_in,
                              void* d_out, int out_size, void* d_ws, size_t ws_size,
                              hipStream_t stream) {
  const float* x  = (const float*)d_in[0];
  const int* pos  = (const int*)d_in[1];
  const float* Wq = (const float*)d_in[2];
  const float* Wk = (const float*)d_in[3];
  const float* Wv = (const float*)d_in[4];
  const float* Wo = (const float*)d_in[5];

  char* ws = (char*)d_ws;
  short* xb  = (short*)(ws);
  short* wqb = (short*)(ws + 16777216);
  short* wkb = (short*)(ws + 25165824);
  short* wvb = (short*)(ws + 33554432);
  short* wob = (short*)(ws + 41943040);
  short* Qb  = (short*)(ws + 50331648);
  short* Kb  = (short*)(ws + 67108864);
  short* Vb  = (short*)(ws + 83886080);
  short* Ob  = (short*)(ws + 100663296);

  cvt_all<<<24576, 256, 0, stream>>>(x, Wq, Wk, Wv, Wo, xb, wqb, wkb, wvb, wob);

  // fused QKV: 768 blocks (3 mats x 16 M x 16 N) = 3 clean dispatch rounds
  gemm_qkv<<<768, 512, 0, stream>>>(xb, wqb, wkb, wvb, pos, Qb, Kb, Vb);

  attn<<<1024, 256, 0, stream>>>(Qb, Kb, Vb, Ob);   // balanced quads, 40 KB LDS

  // O-projection: 256 blocks (16 M x 16 N) = exactly 1 block/CU
  gemm_o<<<256, 512, 0, stream>>>(Ob, wob, (float*)d_out);
}

// Round 7
// 378.315 us; speedup vs baseline: 2.5729x; 1.0038x over previous
//
#include <hip/hip_runtime.h>
#include <hip/hip_bf16.h>
#include <math.h>

#define BB 2
#define SS 2048
#define DD 2048
#define HH 16
#define DHH 128
#define MM (BB*SS)   // 4096

typedef __attribute__((ext_vector_type(8))) short bf16x8;
typedef __attribute__((ext_vector_type(4))) float f32x4;

#define AS1 __attribute__((address_space(1)))
#define AS3 __attribute__((address_space(3)))
#define GLOAD_LDS16(g, l) __builtin_amdgcn_global_load_lds((const AS1 void*)(g), (AS3 void*)(l), 16, 0, 0)

#if __has_builtin(__builtin_amdgcn_exp2f)
#define EXP2F(x) __builtin_amdgcn_exp2f(x)
#else
#define EXP2F(x) exp2f(x)
#endif

__device__ __forceinline__ float b2f(short s) {
  union { unsigned int u; float f; } v;
  v.u = ((unsigned int)(unsigned short)s) << 16;
  return v.f;
}
__device__ __forceinline__ short f2b(float f) {
  union { float f; unsigned int u; } v; v.f = f;
  unsigned int u = v.u;
  u += 0x7fffu + ((u >> 16) & 1u);   // round-to-nearest-even
  return (short)(u >> 16);
}
// fast round-half-up; valid for non-negative finite values
__device__ __forceinline__ short f2b_fast(float f) {
  union { float f; unsigned int u; } v; v.f = f;
  return (short)((v.u + 0x8000u) >> 16);
}

// ---- DPP helpers (VALU pipe, no LDS ops) ----
template<int CTRL>
__device__ __forceinline__ float dppf(float x) {
  int xi = __builtin_bit_cast(int, x);
  int r = __builtin_amdgcn_update_dpp(0, xi, CTRL, 0xf, 0xf, true);
  return __builtin_bit_cast(float, r);
}
__device__ __forceinline__ float rmax16(float x) {
  x = fmaxf(x, dppf<0xB1>(x));   // quad_perm xor1
  x = fmaxf(x, dppf<0x4E>(x));   // quad_perm xor2
  x = fmaxf(x, dppf<0x141>(x));  // row_half_mirror
  x = fmaxf(x, dppf<0x140>(x));  // row_mirror
  return x;
}
__device__ __forceinline__ float rsum16(float x) {
  x += dppf<0xB1>(x);
  x += dppf<0x4E>(x);
  x += dppf<0x141>(x);
  x += dppf<0x140>(x);
  return x;
}

// ---------------- fp32 -> bf16 convert, all 5 tensors in one launch ----------------
__global__ void cvt_all(const float* __restrict__ x,  const float* __restrict__ wq,
                        const float* __restrict__ wk, const float* __restrict__ wv,
                        const float* __restrict__ wo,
                        short* __restrict__ xb,  short* __restrict__ wqb,
                        short* __restrict__ wkb, short* __restrict__ wvb,
                        short* __restrict__ wob) {
  int i = blockIdx.x * blockDim.x + threadIdx.x;   // float4 index
  const float* src; short* dst; int off;
  if (i < 2097152) { src = x; dst = xb; off = i; }
  else {
    int j = i - 2097152;
    int w = j >> 20; off = j & 1048575;
    src = (w == 0) ? wq : (w == 1) ? wk : (w == 2) ? wv : wo;
    dst = (w == 0) ? wqb : (w == 1) ? wkb : (w == 2) ? wvb : wob;
  }
  float4 v = ((const float4*)src)[i < 2097152 ? off : off];
  short4 o;
  o.x = f2b(v.x); o.y = f2b(v.y); o.z = f2b(v.z); o.w = f2b(v.w);
  ((short4*)dst)[off] = o;
}

// =============== QKV: m201-faithful 256x256 tile, 4-phase-per-K-tile =============
// 8 waves (2M x 4N), wave output 128x64 (intensity 1/42.7), BK=64, LDS 128 KiB
// A[2][256][64] | B[2][256][64] double-buffered. Phase quadrants map to PHYSICAL
// operand halves (A-h0 in P1/P2, A-h1 in P3/P4; B-h0 in P1/P4, B-h1 in P2/P3 regs)
// so each phase can stage exactly one dead half-tile (2 gloads). Stage map:
//   t.P1 -> B(t+1)h0   t.P2 -> A(t+1)h1   t.P3 -> A(t+2)h0   t.P4 -> B(t+2)h1
// vmcnt(6) at P2/P4 only (3 half-tiles in flight, never drains mid-loop);
// verified ledger: every half has >=4-phase issue->use margin. 24 ds_reads/tile
// (all bf live P1->P4). No sched_barrier in the loop (m141), raw s_barriers.
#define QLDA(cb, mtq, mt, kk) (*(const bf16x8*)((const char*)smA + (cb)*32768 + \
    ((mtq)*128 + wm*64 + (mt)*16 + l16)*128 + ((((kk)*64) + quad*16) ^ ((l16 & 7) << 4))))
#define QLDB(cb, ntq, nt, kk) (*(const bf16x8*)((const char*)smB + (cb)*32768 + \
    ((ntq)*128 + wn*32 + (nt)*16 + l16)*128 + ((((kk)*64) + quad*16) ^ ((l16 & 7) << 4))))
#define QSTGA(b, t, h) do { \
    GLOAD_LDS16(aBase + (size_t)((h)*128) * DD + (t)*64,      smA_s + (b)*16384 + ((h)*128)*64 + wst); \
    GLOAD_LDS16(aBase + (size_t)((h)*128 + 64) * DD + (t)*64, smA_s + (b)*16384 + ((h)*128 + 64)*64 + wst); } while(0)
#define QSTGB(b, t, h) do { \
    GLOAD_LDS16(bBase + (size_t)((h)*128) * DD + (t)*64,      smB_s + (b)*16384 + ((h)*128)*64 + wst); \
    GLOAD_LDS16(bBase + (size_t)((h)*128 + 64) * DD + (t)*64, smB_s + (b)*16384 + ((h)*128 + 64)*64 + wst); } while(0)
#define QMFMA(MTQ, NTQ) do { \
    __builtin_amdgcn_s_setprio(1); \
    _Pragma("unroll") \
    for (int mt = 0; mt < 4; ++mt) \
      _Pragma("unroll") \
      for (int nt = 0; nt < 2; ++nt) \
        _Pragma("unroll") \
        for (int kk = 0; kk < 2; ++kk) \
          acc[(MTQ)*4 + mt][(NTQ)*2 + nt] = __builtin_amdgcn_mfma_f32_16x16x32_bf16( \
              af[mt][kk], bf[(NTQ)*2 + nt][kk], acc[(MTQ)*4 + mt][(NTQ)*2 + nt], 0, 0, 0); \
    __builtin_amdgcn_s_setprio(0); } while(0)

__global__ __launch_bounds__(512, 1)
void gemm_qkv(const short* __restrict__ A,
              const short* __restrict__ Wq, const short* __restrict__ Wk,
              const short* __restrict__ Wv, const int* __restrict__ pos,
              short* __restrict__ Qo, short* __restrict__ Ko, short* __restrict__ Vo) {
  __shared__ __align__(16) short sm[65536];   // 128 KiB: A[2][256][64] | B[2][256][64]
  const int tid = threadIdx.x;
  const int lane = tid & 63;
  const int wave = tid >> 6;                  // 0..7
  const int quad = lane >> 4, l16 = lane & 15;
  const int wm = wave >> 2, wn = wave & 3;    // wave tile 128 x 64 (half-scattered)

  // bijective XCD swizzle (384 % 8 == 0): XCD j owns 48 consecutive logical tiles
  const int wid = (blockIdx.x & 7) * 48 + (blockIdx.x >> 3);
  const int wsel = wid >> 7;                  // 0=Q 1=K 2=V (128 tiles per matrix)
  const int idr = wid & 127;
  const int bm = (idr >> 3) * 256;
  const int bn = (idr & 7) * 256;
  const short* Bw = (wsel == 0) ? Wq : (wsel == 1) ? Wk : Wv;
  short* Cout = (wsel == 0) ? Qo : (wsel == 1) ? Ko : Vo;

  short* smA_s = sm;               // A bufs at +0, +16384 shorts (32 KB each)
  short* smB_s = sm + 32768;       // B bufs at +0, +16384 shorts
  const char* smA = (const char*)sm;
  const char* smB = (const char*)(sm + 32768);
  const int wst = wave * 512;      // wave staging base within a 64-row group

  const int srow = tid >> 3;                          // 0..63
  const int scol = ((tid & 7) ^ (srow & 7)) * 8;      // pre-swizzled col (shorts)
  const short* aBase = A  + (size_t)(bm + srow) * DD + scol;
  const short* bBase = Bw + (size_t)(bn + srow) * DD + scol;

  f32x4 acc[8][4] = {};
  bf16x8 af[4][2], bf[4][2];

  // ---- prologue: A0h0,B0h0,B0h1,A0h1,A1h0,B1h1 (12 loads); keep last 6 in flight
  QSTGA(0, 0, 0); QSTGB(0, 0, 0); QSTGB(0, 0, 1);
  QSTGA(0, 0, 1); QSTGA(1, 1, 0); QSTGB(1, 1, 1);
  asm volatile("s_waitcnt vmcnt(6)" ::: "memory");
  __builtin_amdgcn_s_barrier();

  for (int t = 0; t < 32; ++t) {
    const int cb = t & 1, nb = cb ^ 1;
    // ===== P1: quadrant (A-h0, B-h0); stage B(t+1)h0 =====
    #pragma unroll
    for (int mt = 0; mt < 4; ++mt) { af[mt][0] = QLDA(cb, 0, mt, 0); af[mt][1] = QLDA(cb, 0, mt, 1); }
    #pragma unroll
    for (int nt = 0; nt < 2; ++nt) { bf[nt][0] = QLDB(cb, 0, nt, 0); bf[nt][1] = QLDB(cb, 0, nt, 1); }
    if (t + 1 < 32) QSTGB(nb, t + 1, 0);
    asm volatile("s_waitcnt lgkmcnt(8)" ::: "memory");   // 12 reads issued
    __builtin_amdgcn_s_barrier();
    asm volatile("s_waitcnt lgkmcnt(0)" ::: "memory");
    QMFMA(0, 0);
    __builtin_amdgcn_s_barrier();
    // ===== P2: quadrant (A-h0, B-h1); stage A(t+1)h1; counted vmcnt =====
    #pragma unroll
    for (int nt = 0; nt < 2; ++nt) { bf[2+nt][0] = QLDB(cb, 1, nt, 0); bf[2+nt][1] = QLDB(cb, 1, nt, 1); }
    if (t + 1 < 32) QSTGA(nb, t + 1, 1);
    if (t + 2 < 32) asm volatile("s_waitcnt vmcnt(6)" ::: "memory");
    else            asm volatile("s_waitcnt vmcnt(0)" ::: "memory");
    __builtin_amdgcn_s_barrier();
    asm volatile("s_waitcnt lgkmcnt(0)" ::: "memory");
    QMFMA(0, 1);
    __builtin_amdgcn_s_barrier();
    // ===== P3: quadrant (A-h1, B-h1 regs); stage A(t+2)h0 (A-h0[cb] now dead) ====
    #pragma unroll
    for (int mt = 0; mt < 4; ++mt) { af[mt][0] = QLDA(cb, 1, mt, 0); af[mt][1] = QLDA(cb, 1, mt, 1); }
    if (t + 2 < 32) QSTGA(cb, t + 2, 0);
    __builtin_amdgcn_s_barrier();
    asm volatile("s_waitcnt lgkmcnt(0)" ::: "memory");
    QMFMA(1, 1);
    __builtin_amdgcn_s_barrier();
    // ===== P4: quadrant (A-h1, B-h0 regs); stage B(t+2)h1; counted vmcnt ========
    if (t + 2 < 32) {
      QSTGB(cb, t + 2, 1);
      asm volatile("s_waitcnt vmcnt(6)" ::: "memory");
    } else {
      asm volatile("s_waitcnt vmcnt(0)" ::: "memory");
    }
    __builtin_amdgcn_s_barrier();
    QMFMA(1, 0);
    __builtin_amdgcn_s_barrier();
  }

  // ---- RoPE in-register for Q/K (pairs = adjacent lanes via DPP xor1) ----
  if (wsel < 2) {
    const float post = (wsel == 0) ? 0.1275174306f : 1.0f;  // log2(e)/sqrt(128)
    float fr[2];
    #pragma unroll
    for (int ntl = 0; ntl < 2; ++ntl) {
      int pi = wn * 16 + ntl * 8 + (l16 >> 1);             // pair index 0..63
      fr[ntl] = __expf(-0.14391156831f * (float)pi);       // theta^(-pi/64)
    }
    const float sgn = (l16 & 1) ? 1.0f : -1.0f;
    #pragma unroll
    for (int MT = 0; MT < 8; ++MT) {
      #pragma unroll
      for (int r = 0; r < 4; ++r) {
        int m = bm + (MT >> 2)*128 + wm*64 + (MT & 3)*16 + quad*4 + r;
        float fp = (float)pos[m & 2047];
        #pragma unroll
        for (int NT = 0; NT < 4; ++NT) {
          float v = acc[MT][NT][r];
          float p = dppf<0xB1>(v);               // partner (d^1) value
          float ang = fp * fr[NT & 1];
          float sn = __sinf(ang), cs = __cosf(ang);
          acc[MT][NT][r] = (v * cs + sgn * p * sn) * post;
        }
      }
    }
  }

  #pragma unroll
  for (int MT = 0; MT < 8; ++MT)
    #pragma unroll
    for (int NT = 0; NT < 4; ++NT)
      #pragma unroll
      for (int r = 0; r < 4; ++r) {
        int m = bm + (MT >> 2)*128 + wm*64 + (MT & 3)*16 + quad*4 + r;
        int n = bn + (NT >> 1)*128 + wn*32 + (NT & 1)*16 + l16;
        int b = m >> 11, s = m & 2047;
        int h = n >> 7,  d = n & 127;
        Cout[(((size_t)(b*HH + h)*SS + s)*DHH) + d] = f2b(acc[MT][NT][r]);
      }
}

// =============== 256x128-tile 8-wave GEMM template (gemm_o, round-6 proven) ======
#define LDA3(b, mt, kk) (*(const bf16x8*)((const char*)smA + (b)*32768 + \
    (wm*64 + (mt)*16 + l16)*128 + ((((kk)*64) + quad*16) ^ ((l16 & 7) << 4))))
#define LDB3(b, nt, kk) (*(const bf16x8*)((const char*)smB + (b)*16384 + \
    (wn*64 + (nt)*16 + l16)*128 + ((((kk)*64) + quad*16) ^ ((l16 & 7) << 4))))
#define STGA4(b, t) do { \
    _Pragma("unroll") \
    for (int h = 0; h < 4; ++h) \
      GLOAD_LDS16(aBase + (size_t)(h*64) * DD + (t)*64, smA + (b)*16384 + h*4096 + wst); } while(0)
#define STGB2M(b, t) do { \
    _Pragma("unroll") \
    for (int h = 0; h < 2; ++h) \
      GLOAD_LDS16(bBase + (size_t)(h*64) * DD + (t)*64, smB + (b)*8192 + h*4096 + wst); } while(0)
#define MFMA_P(NT0) do { \
    __builtin_amdgcn_s_setprio(1); \
    _Pragma("unroll") \
    for (int mt = 0; mt < 4; ++mt) \
      _Pragma("unroll") \
      for (int nt = 0; nt < 2; ++nt) \
        _Pragma("unroll") \
        for (int kk = 0; kk < 2; ++kk) \
          acc[mt][(NT0) + nt] = __builtin_amdgcn_mfma_f32_16x16x32_bf16( \
              af[mt][kk], bf[(NT0) + nt][kk], acc[mt][(NT0) + nt], 0, 0, 0); \
    __builtin_amdgcn_s_setprio(0); } while(0)

#define GEMM_KLOOP \
  STGA4(0, 0); STGB2M(0, 0); \
  STGA4(1, 1); STGB2M(1, 1); \
  asm volatile("s_waitcnt vmcnt(6)" ::: "memory"); \
  __builtin_amdgcn_s_barrier(); \
  int bc = 0, bs = 2; \
  for (int t = 0; t < 32; ++t) { \
    _Pragma("unroll") \
    for (int mt = 0; mt < 4; ++mt) { af[mt][0] = LDA3(bc, mt, 0); af[mt][1] = LDA3(bc, mt, 1); } \
    _Pragma("unroll") \
    for (int nt = 0; nt < 2; ++nt) { bf[nt][0] = LDB3(bc, nt, 0); bf[nt][1] = LDB3(bc, nt, 1); } \
    if (t + 2 < 32) STGA4(bs, t + 2); \
    __builtin_amdgcn_s_barrier(); \
    asm volatile("s_waitcnt lgkmcnt(0)" ::: "memory"); \
    __builtin_amdgcn_sched_barrier(0); \
    MFMA_P(0); \
    __builtin_amdgcn_s_barrier(); \
    _Pragma("unroll") \
    for (int nt = 2; nt < 4; ++nt) { bf[nt][0] = LDB3(bc, nt, 0); bf[nt][1] = LDB3(bc, nt, 1); } \
    if (t + 2 < 32) { \
      STGB2M(bs, t + 2); \
      asm volatile("s_waitcnt vmcnt(6)" ::: "memory"); \
    } else { \
      asm volatile("s_waitcnt vmcnt(0)" ::: "memory"); \
    } \
    __builtin_amdgcn_s_barrier(); \
    asm volatile("s_waitcnt lgkmcnt(0)" ::: "memory"); \
    __builtin_amdgcn_sched_barrier(0); \
    MFMA_P(2); \
    __builtin_amdgcn_s_barrier(); \
    bc = (bc == 2) ? 0 : bc + 1; \
    bs = (bs == 2) ? 0 : bs + 1; \
  }

// ---------------- O-projection GEMM: 256x128 tiles, 256 blocks = 1/CU -----------
__global__ __launch_bounds__(512, 1)
void gemm_o(const short* __restrict__ A, const short* __restrict__ Bw,
            float* __restrict__ Cout) {
  __shared__ __align__(16) short sm[73728];   // 144 KiB
  const int tid = threadIdx.x;
  const int lane = tid & 63;
  const int wave = tid >> 6;
  const int quad = lane >> 4, l16 = lane & 15;
  const int wm = wave >> 1, wn = wave & 1;

  const int wid = (blockIdx.x & 7) * 32 + (blockIdx.x >> 3);  // 256 % 8 == 0
  const int bm = (wid >> 4) * 256;
  const int bn = (wid & 15) * 128;

  short* smA = sm;
  short* smB = sm + 49152;
  const int wst = wave * 512;

  const int srow = tid >> 3;
  const int scol = ((tid & 7) ^ (srow & 7)) * 8;
  const short* aBase = A  + (size_t)(bm + srow) * DD + scol;
  const short* bBase = Bw + (size_t)(bn + srow) * DD + scol;

  f32x4 acc[4][4] = {};
  bf16x8 af[4][2], bf[4][2];

  GEMM_KLOOP

  #pragma unroll
  for (int mt = 0; mt < 4; ++mt)
    #pragma unroll
    for (int nt = 0; nt < 4; ++nt)
      #pragma unroll
      for (int r = 0; r < 4; ++r) {
        int m = bm + wm*64 + mt*16 + quad*4 + r;
        int n = bn + wn*64 + nt*16 + l16;
        Cout[(size_t)m * DD + n] = acc[mt][nt][r];
      }
}

// ---------------- Flash attention (causal), one 64-row Q tile per block ----------
// 256 threads (4 waves); all waves active every iteration. Balanced grid:
// co-resident quads {s,s+8,s+16,s+24} sum to 66 k-tile units, same bh.
// Spill-free design: K staged via global_load_lds (pre-swizzled source, no kreg);
// V reg-prefetch (16 VGPR) with counted vmcnt(4) kept in flight across barrier;
// plain online softmax (exp2 domain). launch_bounds(256,3): no forced spill.
__global__ __launch_bounds__(256, 3)
void attn(const short* __restrict__ Q, const short* __restrict__ K,
          const short* __restrict__ V, short* __restrict__ O) {
  __shared__ __align__(16) short Ks[64*128];    // 16 KB [key][dim], swizzled
  __shared__ __align__(16) short Vt[128*64];    // 16 KB [dim][key], swizzled
  __shared__ __align__(16) short Pb[4*16*64];   // 8 KB per-wave P, swizzled
  const int tid = threadIdx.x;
  const int lane = tid & 63, wave = tid >> 6;   // wave 0..3
  const int quad = lane >> 4, l16 = lane & 15;
  const int L = blockIdx.x;
  const int bh = L & 31;
  const int s = L >> 5;                         // 0..31
  const int qt = (s < 8) ? 31 - s : (s < 16) ? s - 8 : (s < 24) ? 39 - s : s - 16;
  const int b = bh >> 4, h = bh & 15;
  const short* Kg = K + (size_t)bh * SS * DHH;
  const short* Vg = V + (size_t)bh * SS * DHH;
  const int qbase = qt * 64 + wave * 16;

  bf16x8 aq[4];
  {
    const short* qp = Q + ((size_t)bh * SS + qbase + l16) * DHH + quad*8;
    #pragma unroll
    for (int ks = 0; ks < 4; ++ks) aq[ks] = *(const bf16x8*)(qp + ks*32);
  }

  f32x4 o[8] = {};
  float mrow[4], lrow[4];
  #pragma unroll
  for (int r = 0; r < 4; ++r) { mrow[r] = -1e30f; lrow[r] = 0.f; }

  const int skey0 = wave*16 + (lane >> 4);
  const int scolb = (lane & 15) << 4;
  const int vkp = (tid & 31) * 2;
  const int vds = (tid >> 5) * 16;

  const int nkt = qt + 1;
  int4 vreg[4];
  {
    const short* vp = Vg + (size_t)vkp * DHH + vds;
    vreg[0] = *(const int4*)vp;         vreg[1] = *(const int4*)(vp + 8);
    vreg[2] = *(const int4*)(vp + DHH); vreg[3] = *(const int4*)(vp + DHH + 8);
  }

  for (int kt = 0; kt < nkt; ++kt) {
    // ---- stage K(kt) direct to LDS (async, 4 x 1KB/wave) ----
    {
      const short* Kt = Kg + (size_t)kt * 64 * DHH;
      #pragma unroll
      for (int j = 0; j < 4; ++j) {
        int key = skey0 + j*4;
        GLOAD_LDS16(Kt + (size_t)key * DHH + ((scolb ^ ((key & 7) << 4)) >> 1),
                    Ks + wave*2048 + j*512);
      }
    }
    asm volatile("" ::: "memory");   // pin: V loads must issue AFTER K gloads
    // ---- V(kt): transpose-write from regs, swizzled ----
    {
      const short* s0 = (const short*)&vreg[0];   // key vkp,   dims vds..+15
      const short* s1 = (const short*)&vreg[2];   // key vkp+1, dims vds..+15
      #pragma unroll
      for (int e = 0; e < 16; ++e) {
        int dim = vds + e;
        int val = (int)(unsigned short)s0[e] | ((int)(unsigned short)s1[e] << 16);
        *(int*)((char*)Vt + dim*128 + ((vkp*2) ^ ((dim & 7) << 4))) = val;
      }
    }
    // ---- prefetch V(kt+1) into regs; counted wait keeps it in flight ----
    if (kt + 1 < nkt) {
      const short* vp = Vg + (size_t)((kt+1)*64 + vkp) * DHH + vds;
      vreg[0] = *(const int4*)vp;         vreg[1] = *(const int4*)(vp + 8);
      vreg[2] = *(const int4*)(vp + DHH); vreg[3] = *(const int4*)(vp + DHH + 8);
      asm volatile("s_waitcnt vmcnt(4) lgkmcnt(0)" ::: "memory");  // K done, V in flight
    } else {
      asm volatile("s_waitcnt vmcnt(0) lgkmcnt(0)" ::: "memory");
    }
    __builtin_amdgcn_s_barrier();
    __builtin_amdgcn_sched_barrier(0);

    // ---- QK^T: 16 queries x 64 keys ----
    float sv[4][4];
    __builtin_amdgcn_s_setprio(1);
    #pragma unroll
    for (int nt = 0; nt < 4; ++nt) {
      f32x4 a = {0.f, 0.f, 0.f, 0.f};
      #pragma unroll
      for (int ks = 0; ks < 4; ++ks) {
        int key = nt*16 + l16;
        bf16x8 bk = *(const bf16x8*)((const char*)Ks + key*256 +
                       ((ks*64 + quad*16) ^ ((key & 7) << 4)));
        a = __builtin_amdgcn_mfma_f32_16x16x32_bf16(aq[ks], bk, a, 0, 0, 0);
      }
      #pragma unroll
      for (int r = 0; r < 4; ++r) sv[nt][r] = a[r];
    }
    __builtin_amdgcn_s_setprio(0);

    // ---- causal mask on the diagonal tile ----
    if (kt == qt) {
      #pragma unroll
      for (int nt = 0; nt < 4; ++nt)
        #pragma unroll
        for (int r = 0; r < 4; ++r)
          if (nt*16 + l16 > wave*16 + quad*4 + r) sv[nt][r] = -1e30f;
    }

    // ---- online softmax (exp2 domain, plain rescale) ----
    #pragma unroll
    for (int r = 0; r < 4; ++r) {
      float mx = fmaxf(fmaxf(sv[0][r], sv[1][r]), fmaxf(sv[2][r], sv[3][r]));
      mx = rmax16(mx);
      float mnew = fmaxf(mrow[r], mx);
      float alpha = EXP2F(mrow[r] - mnew);
      float ls = 0.f;
      #pragma unroll
      for (int nt = 0; nt < 4; ++nt) {
        float pv = EXP2F(sv[nt][r] - mnew);
        sv[nt][r] = pv; ls += pv;
      }
      ls = rsum16(ls);
      lrow[r] = lrow[r] * alpha + ls;
      mrow[r] = mnew;
      #pragma unroll
      for (int nt = 0; nt < 8; ++nt) o[nt][r] *= alpha;
    }

    // ---- P -> LDS (per-wave region, swizzled) ----
    #pragma unroll
    for (int nt = 0; nt < 4; ++nt)
      #pragma unroll
      for (int r = 0; r < 4; ++r) {
        int qr = quad*4 + r;
        *(short*)((char*)Pb + wave*2048 + qr*128 +
                  (((nt*16 + l16)*2) ^ ((qr & 7) << 4))) = f2b_fast(sv[nt][r]);
      }

    bf16x8 ap[2];
    #pragma unroll
    for (int k2 = 0; k2 < 2; ++k2)
      ap[k2] = *(const bf16x8*)((const char*)Pb + wave*2048 + l16*128 +
                  ((k2*64 + quad*16) ^ ((l16 & 7) << 4)));

    // ---- PV ----
    __builtin_amdgcn_s_setprio(1);
    #pragma unroll
    for (int k2 = 0; k2 < 2; ++k2)
      #pragma unroll
      for (int nt = 0; nt < 8; ++nt) {
        int d = nt*16 + l16;
        bf16x8 bv = *(const bf16x8*)((const char*)Vt + d*128 +
                       ((k2*64 + quad*16) ^ ((d & 7) << 4)));
        o[nt] = __builtin_amdgcn_mfma_f32_16x16x32_bf16(ap[k2], bv, o[nt], 0, 0, 0);
      }
    __builtin_amdgcn_s_setprio(0);

    // ---- end of iter: LDS reads drained; V prefetch stays in flight ----
    asm volatile("s_waitcnt lgkmcnt(0)" ::: "memory");
    __builtin_amdgcn_s_barrier();
    __builtin_amdgcn_sched_barrier(0);
  }

  #pragma unroll
  for (int nt = 0; nt < 8; ++nt)
    #pragma unroll
    for (int r = 0; r < 4; ++r) {
      int q = qbase + quad*4 + r;
      float v = o[nt][r] / lrow[r];
      O[((size_t)(b*SS + q)) * DD + h*DHH + nt*16 + l16] = f2b(v);
    }
}

extern "C" void kernel_launch(void* const* d_in, const int* in_sizes, int n_in,
                              void* d_out, int out_size, void* d_ws, size_t ws_size,
                              hipStream_t stream) {
  const float* x  = (const float*)d_in[0];
  const int* pos  = (const int*)d_in[1];
  const float* Wq = (const float*)d_in[2];
  const float* Wk = (const float*)d_in[3];
  const float* Wv = (const float*)d_in[4];
  const float* Wo = (const float*)d_in[5];

  char* ws = (char*)d_ws;
  short* xb  = (short*)(ws);
  short* wqb = (short*)(ws + 16777216);
  short* wkb = (short*)(ws + 25165824);
  short* wvb = (short*)(ws + 33554432);
  short* wob = (short*)(ws + 41943040);
  short* Qb  = (short*)(ws + 50331648);
  short* Kb  = (short*)(ws + 67108864);
  short* Vb  = (short*)(ws + 83886080);
  short* Ob  = (short*)(ws + 100663296);

  cvt_all<<<24576, 256, 0, stream>>>(x, Wq, Wk, Wv, Wo, xb, wqb, wkb, wvb, wob);

  // fused QKV: 384 blocks (3 mats x 16 M x 8 N), 256x256 m201-style 4-phase
  gemm_qkv<<<384, 512, 0, stream>>>(xb, wqb, wkb, wvb, pos, Qb, Kb, Vb);

  attn<<<1024, 256, 0, stream>>>(Qb, Kb, Vb, Ob);   // balanced quads, 40 KB LDS

  // O-projection: 256 blocks (16 M x 16 N) = exactly 1 block/CU
  gemm_o<<<256, 512, 0, stream>>>(Ob, wob, (float*)d_out);
}